// Round 3
// baseline (559.026 us; speedup 1.0000x reference)
//
#include <hip/hip_runtime.h>
#include <math.h>

#define NEG_SLOPE 0.2f

__device__ inline float lrelu(float x) { return x > 0.f ? x : NEG_SLOPE * x; }

typedef __attribute__((ext_vector_type(8))) _Float16 f16x8;
typedef __attribute__((ext_vector_type(4))) float f32x4;
typedef __attribute__((ext_vector_type(2))) float f32x2;
typedef __attribute__((ext_vector_type(4))) _Float16 h16x4;
typedef __attribute__((ext_vector_type(2))) _Float16 h16x2;

// Convert W1[K1,N1], W2[K2,N2] fp32 -> BT [N][K] fp16 (transposed)
__global__ void convW_k(const float* __restrict__ W1, const float* __restrict__ W2,
                        _Float16* __restrict__ BT1, _Float16* __restrict__ BT2)
{
    int i = blockIdx.x * blockDim.x + threadIdx.x;   // 65536 total
    if (i < 32768) {
        int n = i >> 7, k = i & 127;                 // K=128, N=256
        BT1[(size_t)n * 128 + k] = (_Float16)W1[(size_t)k * 256 + n];
    } else {
        int idx = i - 32768;
        int n = idx >> 8, k = idx & 255;             // K=256, N=128
        BT2[(size_t)n * 256 + k] = (_Float16)W2[(size_t)k * 128 + n];
    }
}

// ---- Fused fp16 MFMA GEMM + fp8 out + attention logits -----------------------
// C = A[M,K] @ W[K,N] (fp16 compute, fp32 acc); epilogue writes HB (fp8 e4m3,
// for the edge-gather) and per-row attn logits aS/aD (fp32 from fp32 acc).
// H=4: direct store head=wave; H=1: atomicAdd. AF16: A is already fp16.
template<int N, int K, int H, bool AF16>
__launch_bounds__(256)
__global__ void gemm_fused(const void* __restrict__ A, const _Float16* __restrict__ BT,
                           unsigned char* __restrict__ HB, const float* __restrict__ att_s,
                           const float* __restrict__ att_d, float* __restrict__ aS,
                           float* __restrict__ aD, int M)
{
    constexpr int ITERS = K / 32;
    constexpr int WN = N / 4;
    constexpr int NT = WN / 16;
    constexpr int NCH = (N * 4) / 256;
    __shared__ unsigned short As[64 * 40] __attribute__((aligned(16)));
    __shared__ unsigned short Bs[N * 40] __attribute__((aligned(16)));
    const int t = threadIdx.x;
    const int wave = t >> 6, lane = t & 63;
    const int quad = lane >> 4, l15 = lane & 15;
    const int rowBase = blockIdx.x * 64;

    f32x4 acc[4][NT];
#pragma unroll
    for (int mi = 0; mi < 4; ++mi)
#pragma unroll
        for (int ni = 0; ni < NT; ++ni)
            acc[mi][ni] = (f32x4){0.f, 0.f, 0.f, 0.f};

    const int ar = t >> 2;             // A-stage row 0..63
    const int ak = (t & 3) << 3;       // A-stage k seg 0,8,16,24
    const int bc = (t * NCH) >> 2;     // B-stage column
    const int bks = (t * NCH) & 3;     // B-stage starting chunk

    for (int it = 0; it < ITERS; ++it) {
        // ---- stage A
        {
            int gr = rowBase + ar;
            f16x8 hv;
#pragma unroll
            for (int j = 0; j < 8; ++j) hv[j] = (_Float16)0.f;
            if (gr < M) {
                if constexpr (AF16) {
                    hv = *(const f16x8*)((const _Float16*)A + (size_t)gr * K + it * 32 + ak);
                } else {
                    const float* ap = (const float*)A + (size_t)gr * K + it * 32 + ak;
                    float4 v0 = *(const float4*)ap;
                    float4 v1 = *(const float4*)(ap + 4);
                    hv[0] = (_Float16)v0.x; hv[1] = (_Float16)v0.y;
                    hv[2] = (_Float16)v0.z; hv[3] = (_Float16)v0.w;
                    hv[4] = (_Float16)v1.x; hv[5] = (_Float16)v1.y;
                    hv[6] = (_Float16)v1.z; hv[7] = (_Float16)v1.w;
                }
            }
            *(f16x8*)&As[ar * 40 + ak] = hv;
        }
        // ---- stage B (pre-converted fp16, contiguous copy)
        {
            const _Float16* bp = BT + (size_t)bc * K + it * 32 + bks * 8;
            unsigned short* dp = &Bs[bc * 40 + bks * 8];
#pragma unroll
            for (int j = 0; j < NCH; ++j)
                *(f16x8*)(dp + j * 8) = *(const f16x8*)(bp + j * 8);
        }
        __syncthreads();
        f16x8 af[4], bfr[NT];
#pragma unroll
        for (int mi = 0; mi < 4; ++mi)
            af[mi] = *(const f16x8*)&As[(mi * 16 + l15) * 40 + quad * 8];
#pragma unroll
        for (int ni = 0; ni < NT; ++ni)
            bfr[ni] = *(const f16x8*)&Bs[(wave * WN + ni * 16 + l15) * 40 + quad * 8];
#pragma unroll
        for (int mi = 0; mi < 4; ++mi)
#pragma unroll
            for (int ni = 0; ni < NT; ++ni)
                acc[mi][ni] = __builtin_amdgcn_mfma_f32_16x16x32_f16(
                    af[mi], bfr[ni], acc[mi][ni], 0, 0, 0);
        __syncthreads();
    }
    // ---- epilogue: fp8 store + logits. D layout col=lane&15, row=quad*4+reg
    float asv[NT], adv[NT];
#pragma unroll
    for (int ni = 0; ni < NT; ++ni) {
        int col = wave * WN + ni * 16 + l15;
        asv[ni] = att_s[col];
        adv[ni] = att_d[col];
    }
#pragma unroll
    for (int mi = 0; mi < 4; ++mi) {
#pragma unroll
        for (int r = 0; r < 4; ++r) {
            int row = rowBase + mi * 16 + quad * 4 + r;
            bool ok = row < M;
            float ss = 0.f, sd = 0.f;
#pragma unroll
            for (int ni = 0; ni < NT; ++ni) {
                float v = acc[mi][ni][r];
                ss += v * asv[ni];
                sd += v * adv[ni];
            }
            // fp8 pack: 2 cols per cvt inst (cols are 16 apart -> byte stores)
#pragma unroll
            for (int ni = 0; ni < NT; ni += 2) {
                int pk = __builtin_amdgcn_cvt_pk_fp8_f32(acc[mi][ni][r],
                                                         acc[mi][ni + 1][r], 0, false);
                if (ok) {
                    HB[(size_t)row * N + wave * WN + ni * 16 + l15] =
                        (unsigned char)(pk & 0xff);
                    HB[(size_t)row * N + wave * WN + (ni + 1) * 16 + l15] =
                        (unsigned char)((pk >> 8) & 0xff);
                }
            }
#pragma unroll
            for (int off = 8; off > 0; off >>= 1) {
                ss += __shfl_xor(ss, off);
                sd += __shfl_xor(sd, off);
            }
            if (ok && l15 == 0) {
                if (H == 4) {
                    aS[row * 4 + wave] = ss;
                    aD[row * 4 + wave] = sd;
                } else {
                    atomicAdd(&aS[row], ss);
                    atomicAdd(&aD[row], sd);
                }
            }
        }
    }
}

// =================== CSR build (two-phase counting sort) ========================
__global__ void count_k(const int* __restrict__ dst, int* __restrict__ counts, int E, int Nn)
{
    int e = blockIdx.x * blockDim.x + threadIdx.x;
    if (e >= E + Nn) return;
    int d = (e < E) ? dst[e] : (e - E);
    atomicAdd(&counts[d], 1);
}

__global__ void scan1_k(const int* __restrict__ counts, int* __restrict__ partial,
                        int* __restrict__ bsum, int Nn)
{
    __shared__ int sh[256];
    int i = blockIdx.x * 256 + threadIdx.x;
    int v = (i < Nn) ? counts[i] : 0;
    sh[threadIdx.x] = v;
    __syncthreads();
#pragma unroll
    for (int o = 1; o < 256; o <<= 1) {
        int t = (threadIdx.x >= o) ? sh[threadIdx.x - o] : 0;
        __syncthreads();
        sh[threadIdx.x] += t;
        __syncthreads();
    }
    if (i < Nn) partial[i] = sh[threadIdx.x] - v;
    if (threadIdx.x == 255) bsum[blockIdx.x] = sh[255];
}

__global__ void scan2_k(int* __restrict__ bsum, int nb)
{
    __shared__ int sh[256];
    int v = (threadIdx.x < nb) ? bsum[threadIdx.x] : 0;
    sh[threadIdx.x] = v;
    __syncthreads();
#pragma unroll
    for (int o = 1; o < 256; o <<= 1) {
        int t = (threadIdx.x >= o) ? sh[threadIdx.x - o] : 0;
        __syncthreads();
        sh[threadIdx.x] += t;
        __syncthreads();
    }
    if (threadIdx.x < nb) bsum[threadIdx.x] = sh[threadIdx.x] - v;
}

// rowptr/cursor per node + ccursor per 64-node coarse bucket
__global__ void scan3_k(const int* __restrict__ partial, const int* __restrict__ bsum,
                        int* __restrict__ rowptr, int* __restrict__ cursor,
                        int* __restrict__ ccursor, int Nn, int ET)
{
    int i = blockIdx.x * 256 + threadIdx.x;
    if (i < Nn) {
        int v = partial[i] + bsum[i >> 8];
        rowptr[i] = v;
        cursor[i] = v;
        if ((i & 63) == 0) ccursor[i >> 6] = v;
    }
    if (i == Nn) rowptr[Nn] = ET;
}

// phase 1: coarse scatter into 64-node buckets; pack (dst&63)<<16 | src (src<65536)
__global__ void binpass_k(const int* __restrict__ src, const int* __restrict__ dst,
                          int* __restrict__ ccursor, int* __restrict__ tmp, int E, int Nn)
{
    int e = blockIdx.x * blockDim.x + threadIdx.x;
    if (e >= E + Nn) return;
    int s, d;
    if (e < E) { s = src[e]; d = dst[e]; } else { s = e - E; d = s; }
    int pos = atomicAdd(&ccursor[d >> 6], 1);
    tmp[pos] = s | ((d & 63) << 16);
}

// phase 2: fine placement within one coarse bucket (block-local 2-4 KB window)
__global__ void fine_k(const int* __restrict__ rowptr, const int* __restrict__ tmp,
                       int* __restrict__ cursor, unsigned short* __restrict__ esrc, int Nn)
{
    int b = blockIdx.x;
    int n0 = b << 6;
    int base = rowptr[n0];
    int end = rowptr[min(n0 + 64, Nn)];
    for (int i = base + (int)threadIdx.x; i < end; i += 256) {
        int v = tmp[i];
        int node = n0 + (v >> 16);
        int pos = atomicAdd(&cursor[node], 1);
        esrc[pos] = (unsigned short)(v & 0xffff);
    }
}

// ===== gather layer 1, fp8 h, online softmax, 8-edge unroll, fp16 out ==========
// Edge ids are wave-uniform: readfirstlane pushes gather addressing to SALU/SMEM.
__global__ void gather1_k(const int* __restrict__ rp, const unsigned short* __restrict__ esrc,
                          const unsigned char* __restrict__ hb, const float* __restrict__ aS,
                          const float* __restrict__ aD, const float* __restrict__ bias,
                          _Float16* __restrict__ out, int Nn)
{
    int d = blockIdx.x * 4 + (threadIdx.x >> 6);
    int lane = threadIdx.x & 63;
    if (d >= Nn) return;
    int c4 = lane << 2;                 // channel base = byte offset (fp8)
    int head = lane >> 4;
    int p0 = __builtin_amdgcn_readfirstlane(rp[d]);
    int p1 = __builtin_amdgcn_readfirstlane(rp[d + 1]);
    float adh = aD[d * 4 + head];
    const float* aSh = aS + head;
    float m = -1e30f, den = 0.f;
    float ax = 0.f, ay = 0.f, az = 0.f, aw = 0.f;
    int p = p0;
    for (; p + 8 <= p1; p += 8) {
        int s[8];
        float l[8];
#pragma unroll
        for (int j = 0; j < 8; ++j) s[j] = __builtin_amdgcn_readfirstlane(esrc[p + j]);
#pragma unroll
        for (int j = 0; j < 8; ++j) l[j] = lrelu(aSh[s[j] * 4] + adh);
        float lm = l[0];
#pragma unroll
        for (int j = 1; j < 8; ++j) lm = fmaxf(lm, l[j]);
        if (lm > m) {
            float r = __expf(m - lm);
            ax *= r; ay *= r; az *= r; aw *= r; den *= r;
            m = lm;
        }
        unsigned int v[8];
#pragma unroll
        for (int j = 0; j < 8; ++j)
            v[j] = *(const unsigned int*)&hb[(size_t)s[j] * 256 + c4];
#pragma unroll
        for (int j = 0; j < 8; ++j) {
            float w = __expf(l[j] - m);
            den += w;
            f32x2 lo = __builtin_amdgcn_cvt_pk_f32_fp8((int)v[j], false);
            f32x2 hi = __builtin_amdgcn_cvt_pk_f32_fp8((int)v[j], true);
            ax += lo[0] * w;
            ay += lo[1] * w;
            az += hi[0] * w;
            aw += hi[1] * w;
        }
    }
    for (; p < p1; ++p) {
        int s0 = __builtin_amdgcn_readfirstlane(esrc[p]);
        float l0 = lrelu(aSh[s0 * 4] + adh);
        if (l0 > m) {
            float r = __expf(m - l0);
            ax *= r; ay *= r; az *= r; aw *= r; den *= r;
            m = l0;
        }
        float w0 = __expf(l0 - m);
        den += w0;
        unsigned int v0 = *(const unsigned int*)&hb[(size_t)s0 * 256 + c4];
        f32x2 lo = __builtin_amdgcn_cvt_pk_f32_fp8((int)v0, false);
        f32x2 hi = __builtin_amdgcn_cvt_pk_f32_fp8((int)v0, true);
        ax += lo[0] * w0; ay += lo[1] * w0;
        az += hi[0] * w0; aw += hi[1] * w0;
    }
    float inv = 1.f / (den + 1e-16f);
    float4 b4 = *(const float4*)&bias[c4];
    float rx, ry, rz, rw;
    rx = ax * inv + b4.x; rx = rx > 0.f ? rx : expm1f(rx);
    ry = ay * inv + b4.y; ry = ry > 0.f ? ry : expm1f(ry);
    rz = az * inv + b4.z; rz = rz > 0.f ? rz : expm1f(rz);
    rw = aw * inv + b4.w; rw = rw > 0.f ? rw : expm1f(rw);
    h16x4 r16;
    r16[0] = (_Float16)rx; r16[1] = (_Float16)ry;
    r16[2] = (_Float16)rz; r16[3] = (_Float16)rw;
    *(h16x4*)&out[(size_t)d * 256 + c4] = r16;
}

// ===== gather layer 2: full wave per dst, 2 ch/lane, fp8 h =====================
__global__ void gather2_k(const int* __restrict__ rp, const unsigned short* __restrict__ esrc,
                          const unsigned char* __restrict__ hb, const float* __restrict__ aS,
                          const float* __restrict__ aD, _Float16* __restrict__ out, int Nn)
{
    int d = blockIdx.x * 4 + (threadIdx.x >> 6);
    int lane = threadIdx.x & 63;
    if (d >= Nn) return;
    int c2 = lane << 1;                 // channel base = byte offset (fp8)
    int p0 = __builtin_amdgcn_readfirstlane(rp[d]);
    int p1 = __builtin_amdgcn_readfirstlane(rp[d + 1]);
    float adh = aD[d];
    float m = -1e30f, den = 0.f;
    float ax = 0.f, ay = 0.f;
    int p = p0;
    for (; p + 8 <= p1; p += 8) {
        int s[8];
        float l[8];
#pragma unroll
        for (int j = 0; j < 8; ++j) s[j] = __builtin_amdgcn_readfirstlane(esrc[p + j]);
#pragma unroll
        for (int j = 0; j < 8; ++j) l[j] = lrelu(aS[s[j]] + adh);
        float lm = l[0];
#pragma unroll
        for (int j = 1; j < 8; ++j) lm = fmaxf(lm, l[j]);
        if (lm > m) {
            float r = __expf(m - lm);
            ax *= r; ay *= r; den *= r;
            m = lm;
        }
        unsigned short v[8];
#pragma unroll
        for (int j = 0; j < 8; ++j)
            v[j] = *(const unsigned short*)&hb[(size_t)s[j] * 128 + c2];
#pragma unroll
        for (int j = 0; j < 8; ++j) {
            float w = __expf(l[j] - m);
            den += w;
            f32x2 lo = __builtin_amdgcn_cvt_pk_f32_fp8((int)v[j], false);
            ax += lo[0] * w;
            ay += lo[1] * w;
        }
    }
    for (; p < p1; ++p) {
        int s0 = __builtin_amdgcn_readfirstlane(esrc[p]);
        float l0 = lrelu(aS[s0] + adh);
        if (l0 > m) {
            float r = __expf(m - l0);
            ax *= r; ay *= r; den *= r;
            m = l0;
        }
        float w0 = __expf(l0 - m);
        den += w0;
        unsigned short v0 = *(const unsigned short*)&hb[(size_t)s0 * 128 + c2];
        f32x2 lo = __builtin_amdgcn_cvt_pk_f32_fp8((int)v0, false);
        ax += lo[0] * w0;
        ay += lo[1] * w0;
    }
    float inv = 1.f / (den + 1e-16f);
    h16x2 r16;
    r16[0] = (_Float16)(ax * inv);
    r16[1] = (_Float16)(ay * inv);
    *(h16x2*)&out[(size_t)d * 128 + c2] = r16;
}

// batch is sorted; per-block run-length accumulate then atomicAdd per graph run
__global__ void pool_k(const _Float16* __restrict__ o2, const float* __restrict__ b2,
                       const int* __restrict__ batch, float* __restrict__ sums, int Nn, int C)
{
    int c = threadIdx.x;               // C = 128
    int n0 = blockIdx.x * 64;
    int n1 = min(n0 + 64, Nn);
    float local = 0.f;
    int gcur = batch[n0];
    float bc = b2[c];
    for (int n = n0; n < n1; ++n) {
        int g = batch[n];
        if (g != gcur) {
            atomicAdd(&sums[gcur * C + c], local);
            local = 0.f;
            gcur = g;
        }
        float v = (float)o2[(size_t)n * C + c] + bc;
        local += v > 0.f ? v : expm1f(v);
    }
    atomicAdd(&sums[gcur * C + c], local);
}

__global__ void final_k(const float* __restrict__ sums, const int* __restrict__ batch,
                        const float* __restrict__ lin_w, const float* __restrict__ lin_b,
                        float* __restrict__ out, int Nn, int G, int C, int NC)
{
    __shared__ float inv[64];
    int t = threadIdx.x;
    if (t < G) {
        int lo = 0, hi = Nn;
        while (lo < hi) { int mid = (lo + hi) >> 1; if (batch[mid] < t) lo = mid + 1; else hi = mid; }
        int lb = lo;
        lo = 0; hi = Nn;
        while (lo < hi) { int mid = (lo + hi) >> 1; if (batch[mid] < t + 1) lo = mid + 1; else hi = mid; }
        int cnt = lo - lb;
        inv[t] = 1.f / fmaxf((float)cnt, 1.f);
    }
    __syncthreads();
    if (t < G * NC) {
        int g = t / NC, k = t % NC;
        float acc = 0.f;
        for (int c = 0; c < C; ++c) acc += sums[g * C + c] * lin_w[c * NC + k];
        out[t] = acc * inv[g] + lin_b[k];
    }
}

extern "C" void kernel_launch(void* const* d_in, const int* in_sizes, int n_in,
                              void* d_out, int out_size, void* d_ws, size_t ws_size,
                              hipStream_t stream)
{
    const float* x      = (const float*)d_in[0];
    const int*   eidx   = (const int*)d_in[1];
    const int*   batch  = (const int*)d_in[2];
    const float* W1     = (const float*)d_in[3];
    const float* att_s1 = (const float*)d_in[4];
    const float* att_d1 = (const float*)d_in[5];
    const float* b1     = (const float*)d_in[6];
    const float* W2     = (const float*)d_in[7];
    const float* att_s2 = (const float*)d_in[8];
    const float* att_d2 = (const float*)d_in[9];
    const float* b2     = (const float*)d_in[10];
    const float* lin_w  = (const float*)d_in[11];
    const float* lin_b  = (const float*)d_in[12];

    const int Nn  = in_sizes[2];         // 50000
    const int E   = in_sizes[1] / 2;     // 800000
    const int H1_ = 4, C1_ = 64, C2_ = 128, G = 32, NC = 5;
    const int D1 = H1_ * C1_;            // 256
    const int ET = E + Nn;
    const int NBUCK = (Nn + 63) >> 6;    // 782 coarse buckets

    const int* srcp = eidx;
    const int* dstp = eidx + E;

    float* ws = (float*)d_ws;
    size_t off = 0;
    auto alloc = [&](size_t n) { float* p = ws + off; off += n; return p; };
    _Float16* o1h = (_Float16*)alloc((size_t)Nn * D1 / 2);    // fp16 layer-1 out
    _Float16* o2h = (_Float16*)alloc((size_t)Nn * C2_ / 2);   // fp16 layer-2 out
    float* aS1  = alloc((size_t)Nn * H1_);
    float* aD1  = alloc((size_t)Nn * H1_);
    float* aS2  = alloc(Nn);              // contiguous with aD2 for single memset
    float* aD2  = alloc(Nn);
    float* sums = alloc((size_t)G * C2_);
    _Float16* BT1 = (_Float16*)alloc(D1 * 128 / 2);           // [256][128] fp16
    _Float16* BT2 = (_Float16*)alloc(C2_ * 256 / 2);          // [128][256] fp16
    unsigned char* hb1 = (unsigned char*)alloc((size_t)Nn * D1 / 4);   // fp8 h1
    unsigned char* hb2 = (unsigned char*)alloc((size_t)Nn * C2_ / 4);  // fp8 h2
    int* iws    = (int*)(ws + off);
    int* counts = iws;
    int* partial= iws + Nn;
    int* rowptr = iws + 2 * Nn;          // Nn+1
    int* cursor = iws + 3 * Nn + 1;      // Nn
    int* bsum   = iws + 4 * Nn + 1;      // 256
    int* ccursor= iws + 4 * Nn + 1 + 256;           // NBUCK (<=1024)
    int* tmp    = iws + 4 * Nn + 1 + 256 + 1024;    // ET packed edges
    unsigned short* esrc = (unsigned short*)(tmp + ET);  // ET u16 srcs

    const int NB = (Nn + 255) / 256;
    const int GB = (Nn + 63) / 64;

    // ---------------- CSR build (two-phase counting sort) ----------------
    hipMemsetAsync(counts, 0, (size_t)Nn * 4, stream);
    hipMemsetAsync(aS2, 0, (size_t)2 * Nn * 4, stream);   // aS2+aD2 (gemm2 atomics)
    count_k<<<(ET + 255) / 256, 256, 0, stream>>>(dstp, counts, E, Nn);
    scan1_k<<<NB, 256, 0, stream>>>(counts, partial, bsum, Nn);
    scan2_k<<<1, 256, 0, stream>>>(bsum, NB);
    scan3_k<<<(Nn + 256) / 256, 256, 0, stream>>>(partial, bsum, rowptr, cursor,
                                                  ccursor, Nn, ET);
    binpass_k<<<(ET + 255) / 256, 256, 0, stream>>>(srcp, dstp, ccursor, tmp, E, Nn);
    fine_k<<<NBUCK, 256, 0, stream>>>(rowptr, tmp, cursor, esrc, Nn);

    // ---------------- weight transpose+convert (fp16) ----------------
    convW_k<<<256, 256, 0, stream>>>(W1, W2, BT1, BT2);

    // ---------------- layer 1: fp16 GEMM + fp8 out + logits fused ----------------
    gemm_fused<256, 128, 4, false><<<GB, 256, 0, stream>>>(x, BT1, hb1, att_s1, att_d1,
                                                           aS1, aD1, Nn);
    gather1_k<<<(Nn + 3) / 4, 256, 0, stream>>>(rowptr, esrc, hb1, aS1, aD1, b1, o1h, Nn);

    // ---------------- layer 2: fp16 GEMM + fp8 out + logits fused ----------------
    gemm_fused<128, 256, 1, true><<<GB, 256, 0, stream>>>(o1h, BT2, hb2, att_s2, att_d2,
                                                          aS2, aD2, Nn);
    gather2_k<<<(Nn + 3) / 4, 256, 0, stream>>>(rowptr, esrc, hb2, aS2, aD2, o2h, Nn);

    // ---------------- pool + classifier ----------------
    hipMemsetAsync(sums, 0, (size_t)G * C2_ * 4, stream);
    pool_k<<<GB, C2_, 0, stream>>>(o2h, b2, batch, sums, Nn, C2_);
    final_k<<<1, 256, 0, stream>>>(sums, batch, lin_w, lin_b, (float*)d_out, Nn, G, C2_, NC);
}

// Round 4
// 347.860 us; speedup vs baseline: 1.6070x; 1.6070x over previous
//
#include <hip/hip_runtime.h>
#include <math.h>

#define NEG_SLOPE 0.2f

__device__ inline float lrelu(float x) { return x > 0.f ? x : NEG_SLOPE * x; }

typedef __attribute__((ext_vector_type(8))) _Float16 f16x8;
typedef __attribute__((ext_vector_type(4))) float f32x4;
typedef __attribute__((ext_vector_type(2))) float f32x2;
typedef __attribute__((ext_vector_type(4))) _Float16 h16x4;
typedef __attribute__((ext_vector_type(2))) _Float16 h16x2;

// Convert W1[K1,N1], W2[K2,N2] fp32 -> BT [N][K] fp16 (transposed)
__global__ void convW_k(const float* __restrict__ W1, const float* __restrict__ W2,
                        _Float16* __restrict__ BT1, _Float16* __restrict__ BT2)
{
    int i = blockIdx.x * blockDim.x + threadIdx.x;   // 65536 total
    if (i < 32768) {
        int n = i >> 7, k = i & 127;                 // K=128, N=256
        BT1[(size_t)n * 128 + k] = (_Float16)W1[(size_t)k * 256 + n];
    } else {
        int idx = i - 32768;
        int n = idx >> 8, k = idx & 255;             // K=256, N=128
        BT2[(size_t)n * 256 + k] = (_Float16)W2[(size_t)k * 128 + n];
    }
}

// ---- Fused fp16 MFMA GEMM + fp8 out + attention logits -----------------------
// C = A[M,K] @ W[K,N] (fp16 compute, fp32 acc); epilogue writes HB (fp8 e4m3,
// for the edge-gather) and per-row attn logits aS/aD (fp32 from fp32 acc).
// H=4: direct store head=wave; H=1: atomicAdd. AF16: A is already fp16.
template<int N, int K, int H, bool AF16>
__launch_bounds__(256)
__global__ void gemm_fused(const void* __restrict__ A, const _Float16* __restrict__ BT,
                           unsigned char* __restrict__ HB, const float* __restrict__ att_s,
                           const float* __restrict__ att_d, float* __restrict__ aS,
                           float* __restrict__ aD, int M)
{
    constexpr int ITERS = K / 32;
    constexpr int WN = N / 4;
    constexpr int NT = WN / 16;
    constexpr int NCH = (N * 4) / 256;
    __shared__ unsigned short As[64 * 40] __attribute__((aligned(16)));
    __shared__ unsigned short Bs[N * 40] __attribute__((aligned(16)));
    const int t = threadIdx.x;
    const int wave = t >> 6, lane = t & 63;
    const int quad = lane >> 4, l15 = lane & 15;
    const int rowBase = blockIdx.x * 64;

    f32x4 acc[4][NT];
#pragma unroll
    for (int mi = 0; mi < 4; ++mi)
#pragma unroll
        for (int ni = 0; ni < NT; ++ni)
            acc[mi][ni] = (f32x4){0.f, 0.f, 0.f, 0.f};

    const int ar = t >> 2;             // A-stage row 0..63
    const int ak = (t & 3) << 3;       // A-stage k seg 0,8,16,24
    const int bc = (t * NCH) >> 2;     // B-stage column
    const int bks = (t * NCH) & 3;     // B-stage starting chunk

    for (int it = 0; it < ITERS; ++it) {
        // ---- stage A
        {
            int gr = rowBase + ar;
            f16x8 hv;
#pragma unroll
            for (int j = 0; j < 8; ++j) hv[j] = (_Float16)0.f;
            if (gr < M) {
                if constexpr (AF16) {
                    hv = *(const f16x8*)((const _Float16*)A + (size_t)gr * K + it * 32 + ak);
                } else {
                    const float* ap = (const float*)A + (size_t)gr * K + it * 32 + ak;
                    float4 v0 = *(const float4*)ap;
                    float4 v1 = *(const float4*)(ap + 4);
                    hv[0] = (_Float16)v0.x; hv[1] = (_Float16)v0.y;
                    hv[2] = (_Float16)v0.z; hv[3] = (_Float16)v0.w;
                    hv[4] = (_Float16)v1.x; hv[5] = (_Float16)v1.y;
                    hv[6] = (_Float16)v1.z; hv[7] = (_Float16)v1.w;
                }
            }
            *(f16x8*)&As[ar * 40 + ak] = hv;
        }
        // ---- stage B (pre-converted fp16, contiguous copy)
        {
            const _Float16* bp = BT + (size_t)bc * K + it * 32 + bks * 8;
            unsigned short* dp = &Bs[bc * 40 + bks * 8];
#pragma unroll
            for (int j = 0; j < NCH; ++j)
                *(f16x8*)(dp + j * 8) = *(const f16x8*)(bp + j * 8);
        }
        __syncthreads();
        f16x8 af[4], bfr[NT];
#pragma unroll
        for (int mi = 0; mi < 4; ++mi)
            af[mi] = *(const f16x8*)&As[(mi * 16 + l15) * 40 + quad * 8];
#pragma unroll
        for (int ni = 0; ni < NT; ++ni)
            bfr[ni] = *(const f16x8*)&Bs[(wave * WN + ni * 16 + l15) * 40 + quad * 8];
#pragma unroll
        for (int mi = 0; mi < 4; ++mi)
#pragma unroll
            for (int ni = 0; ni < NT; ++ni)
                acc[mi][ni] = __builtin_amdgcn_mfma_f32_16x16x32_f16(
                    af[mi], bfr[ni], acc[mi][ni], 0, 0, 0);
        __syncthreads();
    }
    // ---- epilogue: fp8 store + logits. D layout col=lane&15, row=quad*4+reg
    float asv[NT], adv[NT];
#pragma unroll
    for (int ni = 0; ni < NT; ++ni) {
        int col = wave * WN + ni * 16 + l15;
        asv[ni] = att_s[col];
        adv[ni] = att_d[col];
    }
#pragma unroll
    for (int mi = 0; mi < 4; ++mi) {
#pragma unroll
        for (int r = 0; r < 4; ++r) {
            int row = rowBase + mi * 16 + quad * 4 + r;
            bool ok = row < M;
            float ss = 0.f, sd = 0.f;
#pragma unroll
            for (int ni = 0; ni < NT; ++ni) {
                float v = acc[mi][ni][r];
                ss += v * asv[ni];
                sd += v * adv[ni];
            }
            // fp8 pack: 2 cols per cvt inst (cols are 16 apart -> byte stores)
#pragma unroll
            for (int ni = 0; ni < NT; ni += 2) {
                int pk = __builtin_amdgcn_cvt_pk_fp8_f32(acc[mi][ni][r],
                                                         acc[mi][ni + 1][r], 0, false);
                if (ok) {
                    HB[(size_t)row * N + wave * WN + ni * 16 + l15] =
                        (unsigned char)(pk & 0xff);
                    HB[(size_t)row * N + wave * WN + (ni + 1) * 16 + l15] =
                        (unsigned char)((pk >> 8) & 0xff);
                }
            }
#pragma unroll
            for (int off = 8; off > 0; off >>= 1) {
                ss += __shfl_xor(ss, off);
                sd += __shfl_xor(sd, off);
            }
            if (ok && l15 == 0) {
                if (H == 4) {
                    aS[row * 4 + wave] = ss;
                    aD[row * 4 + wave] = sd;
                } else {
                    atomicAdd(&aS[row], ss);
                    atomicAdd(&aD[row], sd);
                }
            }
        }
    }
}

// =================== CSR build (two-phase sort, LDS-aggregated) =================
__global__ void count_k(const int* __restrict__ dst, int* __restrict__ counts, int E, int Nn)
{
    int e = blockIdx.x * blockDim.x + threadIdx.x;
    if (e >= E + Nn) return;
    int d = (e < E) ? dst[e] : (e - E);
    atomicAdd(&counts[d], 1);
}

__global__ void scan1_k(const int* __restrict__ counts, int* __restrict__ partial,
                        int* __restrict__ bsum, int Nn)
{
    __shared__ int sh[256];
    int i = blockIdx.x * 256 + threadIdx.x;
    int v = (i < Nn) ? counts[i] : 0;
    sh[threadIdx.x] = v;
    __syncthreads();
#pragma unroll
    for (int o = 1; o < 256; o <<= 1) {
        int t = (threadIdx.x >= o) ? sh[threadIdx.x - o] : 0;
        __syncthreads();
        sh[threadIdx.x] += t;
        __syncthreads();
    }
    if (i < Nn) partial[i] = sh[threadIdx.x] - v;
    if (threadIdx.x == 255) bsum[blockIdx.x] = sh[255];
}

__global__ void scan2_k(int* __restrict__ bsum, int nb)
{
    __shared__ int sh[256];
    int v = (threadIdx.x < nb) ? bsum[threadIdx.x] : 0;
    sh[threadIdx.x] = v;
    __syncthreads();
#pragma unroll
    for (int o = 1; o < 256; o <<= 1) {
        int t = (threadIdx.x >= o) ? sh[threadIdx.x - o] : 0;
        __syncthreads();
        sh[threadIdx.x] += t;
        __syncthreads();
    }
    if (threadIdx.x < nb) bsum[threadIdx.x] = sh[threadIdx.x] - v;
}

// rowptr per node + ccursor per 64-node coarse bucket
__global__ void scan3_k(const int* __restrict__ partial, const int* __restrict__ bsum,
                        int* __restrict__ rowptr, int* __restrict__ ccursor, int Nn, int ET)
{
    int i = blockIdx.x * 256 + threadIdx.x;
    if (i < Nn) {
        int v = partial[i] + bsum[i >> 8];
        rowptr[i] = v;
        if ((i & 63) == 0) ccursor[i >> 6] = v;
    }
    if (i == Nn) rowptr[Nn] = ET;
}

// phase 1: LDS-aggregated coarse scatter. Each block: 8192 edges, LDS histogram
// over 782 buckets, ONE global atomicAdd per (block,bucket), then ranked writes.
// Edge packs fully into u32: src | dst<<16 (both < 65536).
#define BIN_EPT 32
__launch_bounds__(256)
__global__ void binpass_k(const int* __restrict__ src, const int* __restrict__ dst,
                          int* __restrict__ ccursor, unsigned int* __restrict__ tmp,
                          int ET, int E, int NBUCK)
{
    __shared__ int hist[1024];
    for (int i = threadIdx.x; i < NBUCK; i += 256) hist[i] = 0;
    __syncthreads();
    int e0 = blockIdx.x * (256 * BIN_EPT) + threadIdx.x;
    unsigned int ev[BIN_EPT];
    int meta[BIN_EPT];
#pragma unroll
    for (int j = 0; j < BIN_EPT; ++j) {
        int e = e0 + j * 256;
        meta[j] = -1;
        if (e < ET) {
            int s, d;
            if (e < E) { s = src[e]; d = dst[e]; } else { s = e - E; d = s; }
            ev[j] = (unsigned int)s | ((unsigned int)d << 16);
            int b = d >> 6;
            int r = atomicAdd(&hist[b], 1);
            meta[j] = (r << 10) | b;          // rank<8192 (13b) | bucket (10b)
        }
    }
    __syncthreads();
    // reserve global ranges: one atomic per touched bucket per block
    for (int i = threadIdx.x; i < NBUCK; i += 256) {
        int c = hist[i];
        hist[i] = (c > 0) ? atomicAdd(&ccursor[i], c) : 0;
    }
    __syncthreads();
#pragma unroll
    for (int j = 0; j < BIN_EPT; ++j) {
        if (meta[j] >= 0) {
            int b = meta[j] & 1023;
            int r = meta[j] >> 10;
            tmp[hist[b] + r] = ev[j];
        }
    }
}

// phase 2: fine placement within one coarse bucket; cursors live in LDS (block
// owns its 64 nodes), writes land in the block's own contiguous u16 window.
__global__ void fine_k(const int* __restrict__ rowptr, const unsigned int* __restrict__ tmp,
                       unsigned short* __restrict__ esrc, int Nn)
{
    __shared__ int lcur[64];
    int n0 = blockIdx.x << 6;
    int nend = min(n0 + 64, Nn);
    if (threadIdx.x < 64) {
        int n = n0 + threadIdx.x;
        lcur[threadIdx.x] = (n < Nn) ? rowptr[n] : 0;
    }
    __syncthreads();
    int base = rowptr[n0];
    int end = rowptr[nend];
    for (int i = base + (int)threadIdx.x; i < end; i += 256) {
        unsigned int v = tmp[i];
        int nl = (v >> 16) & 63;
        int pos = atomicAdd(&lcur[nl], 1);
        esrc[pos] = (unsigned short)(v & 0xffffu);
    }
}

// ===== gather layer 1, fp8 h, online softmax, 8-edge unroll, fp16 out ==========
// Edge ids are wave-uniform: readfirstlane pushes gather addressing to SALU/SMEM.
__global__ void gather1_k(const int* __restrict__ rp, const unsigned short* __restrict__ esrc,
                          const unsigned char* __restrict__ hb, const float* __restrict__ aS,
                          const float* __restrict__ aD, const float* __restrict__ bias,
                          _Float16* __restrict__ out, int Nn)
{
    int d = blockIdx.x * 4 + (threadIdx.x >> 6);
    int lane = threadIdx.x & 63;
    if (d >= Nn) return;
    int c4 = lane << 2;                 // channel base = byte offset (fp8)
    int head = lane >> 4;
    int p0 = __builtin_amdgcn_readfirstlane(rp[d]);
    int p1 = __builtin_amdgcn_readfirstlane(rp[d + 1]);
    float adh = aD[d * 4 + head];
    const float* aSh = aS + head;
    float m = -1e30f, den = 0.f;
    float ax = 0.f, ay = 0.f, az = 0.f, aw = 0.f;
    int p = p0;
    for (; p + 8 <= p1; p += 8) {
        int s[8];
        float l[8];
#pragma unroll
        for (int j = 0; j < 8; ++j) s[j] = __builtin_amdgcn_readfirstlane(esrc[p + j]);
#pragma unroll
        for (int j = 0; j < 8; ++j) l[j] = lrelu(aSh[s[j] * 4] + adh);
        float lm = l[0];
#pragma unroll
        for (int j = 1; j < 8; ++j) lm = fmaxf(lm, l[j]);
        if (lm > m) {
            float r = __expf(m - lm);
            ax *= r; ay *= r; az *= r; aw *= r; den *= r;
            m = lm;
        }
        unsigned int v[8];
#pragma unroll
        for (int j = 0; j < 8; ++j)
            v[j] = *(const unsigned int*)&hb[(size_t)s[j] * 256 + c4];
#pragma unroll
        for (int j = 0; j < 8; ++j) {
            float w = __expf(l[j] - m);
            den += w;
            f32x2 lo = __builtin_amdgcn_cvt_pk_f32_fp8((int)v[j], false);
            f32x2 hi = __builtin_amdgcn_cvt_pk_f32_fp8((int)v[j], true);
            ax += lo[0] * w;
            ay += lo[1] * w;
            az += hi[0] * w;
            aw += hi[1] * w;
        }
    }
    for (; p < p1; ++p) {
        int s0 = __builtin_amdgcn_readfirstlane(esrc[p]);
        float l0 = lrelu(aSh[s0 * 4] + adh);
        if (l0 > m) {
            float r = __expf(m - l0);
            ax *= r; ay *= r; az *= r; aw *= r; den *= r;
            m = l0;
        }
        float w0 = __expf(l0 - m);
        den += w0;
        unsigned int v0 = *(const unsigned int*)&hb[(size_t)s0 * 256 + c4];
        f32x2 lo = __builtin_amdgcn_cvt_pk_f32_fp8((int)v0, false);
        f32x2 hi = __builtin_amdgcn_cvt_pk_f32_fp8((int)v0, true);
        ax += lo[0] * w0; ay += lo[1] * w0;
        az += hi[0] * w0; aw += hi[1] * w0;
    }
    float inv = 1.f / (den + 1e-16f);
    float4 b4 = *(const float4*)&bias[c4];
    float rx, ry, rz, rw;
    rx = ax * inv + b4.x; rx = rx > 0.f ? rx : expm1f(rx);
    ry = ay * inv + b4.y; ry = ry > 0.f ? ry : expm1f(ry);
    rz = az * inv + b4.z; rz = rz > 0.f ? rz : expm1f(rz);
    rw = aw * inv + b4.w; rw = rw > 0.f ? rw : expm1f(rw);
    h16x4 r16;
    r16[0] = (_Float16)rx; r16[1] = (_Float16)ry;
    r16[2] = (_Float16)rz; r16[3] = (_Float16)rw;
    *(h16x4*)&out[(size_t)d * 256 + c4] = r16;
}

// ===== gather layer 2: full wave per dst, 2 ch/lane, fp8 h =====================
__global__ void gather2_k(const int* __restrict__ rp, const unsigned short* __restrict__ esrc,
                          const unsigned char* __restrict__ hb, const float* __restrict__ aS,
                          const float* __restrict__ aD, _Float16* __restrict__ out, int Nn)
{
    int d = blockIdx.x * 4 + (threadIdx.x >> 6);
    int lane = threadIdx.x & 63;
    if (d >= Nn) return;
    int c2 = lane << 1;                 // channel base = byte offset (fp8)
    int p0 = __builtin_amdgcn_readfirstlane(rp[d]);
    int p1 = __builtin_amdgcn_readfirstlane(rp[d + 1]);
    float adh = aD[d];
    float m = -1e30f, den = 0.f;
    float ax = 0.f, ay = 0.f;
    int p = p0;
    for (; p + 8 <= p1; p += 8) {
        int s[8];
        float l[8];
#pragma unroll
        for (int j = 0; j < 8; ++j) s[j] = __builtin_amdgcn_readfirstlane(esrc[p + j]);
#pragma unroll
        for (int j = 0; j < 8; ++j) l[j] = lrelu(aS[s[j]] + adh);
        float lm = l[0];
#pragma unroll
        for (int j = 1; j < 8; ++j) lm = fmaxf(lm, l[j]);
        if (lm > m) {
            float r = __expf(m - lm);
            ax *= r; ay *= r; den *= r;
            m = lm;
        }
        unsigned short v[8];
#pragma unroll
        for (int j = 0; j < 8; ++j)
            v[j] = *(const unsigned short*)&hb[(size_t)s[j] * 128 + c2];
#pragma unroll
        for (int j = 0; j < 8; ++j) {
            float w = __expf(l[j] - m);
            den += w;
            f32x2 lo = __builtin_amdgcn_cvt_pk_f32_fp8((int)v[j], false);
            ax += lo[0] * w;
            ay += lo[1] * w;
        }
    }
    for (; p < p1; ++p) {
        int s0 = __builtin_amdgcn_readfirstlane(esrc[p]);
        float l0 = lrelu(aS[s0] + adh);
        if (l0 > m) {
            float r = __expf(m - l0);
            ax *= r; ay *= r; den *= r;
            m = l0;
        }
        float w0 = __expf(l0 - m);
        den += w0;
        unsigned short v0 = *(const unsigned short*)&hb[(size_t)s0 * 128 + c2];
        f32x2 lo = __builtin_amdgcn_cvt_pk_f32_fp8((int)v0, false);
        ax += lo[0] * w0;
        ay += lo[1] * w0;
    }
    float inv = 1.f / (den + 1e-16f);
    h16x2 r16;
    r16[0] = (_Float16)(ax * inv);
    r16[1] = (_Float16)(ay * inv);
    *(h16x2*)&out[(size_t)d * 128 + c2] = r16;
}

// batch is sorted; per-block run-length accumulate then atomicAdd per graph run
__global__ void pool_k(const _Float16* __restrict__ o2, const float* __restrict__ b2,
                       const int* __restrict__ batch, float* __restrict__ sums, int Nn, int C)
{
    int c = threadIdx.x;               // C = 128
    int n0 = blockIdx.x * 64;
    int n1 = min(n0 + 64, Nn);
    float local = 0.f;
    int gcur = batch[n0];
    float bc = b2[c];
    for (int n = n0; n < n1; ++n) {
        int g = batch[n];
        if (g != gcur) {
            atomicAdd(&sums[gcur * C + c], local);
            local = 0.f;
            gcur = g;
        }
        float v = (float)o2[(size_t)n * C + c] + bc;
        local += v > 0.f ? v : expm1f(v);
    }
    atomicAdd(&sums[gcur * C + c], local);
}

__global__ void final_k(const float* __restrict__ sums, const int* __restrict__ batch,
                        const float* __restrict__ lin_w, const float* __restrict__ lin_b,
                        float* __restrict__ out, int Nn, int G, int C, int NC)
{
    __shared__ float inv[64];
    int t = threadIdx.x;
    if (t < G) {
        int lo = 0, hi = Nn;
        while (lo < hi) { int mid = (lo + hi) >> 1; if (batch[mid] < t) lo = mid + 1; else hi = mid; }
        int lb = lo;
        lo = 0; hi = Nn;
        while (lo < hi) { int mid = (lo + hi) >> 1; if (batch[mid] < t + 1) lo = mid + 1; else hi = mid; }
        int cnt = lo - lb;
        inv[t] = 1.f / fmaxf((float)cnt, 1.f);
    }
    __syncthreads();
    if (t < G * NC) {
        int g = t / NC, k = t % NC;
        float acc = 0.f;
        for (int c = 0; c < C; ++c) acc += sums[g * C + c] * lin_w[c * NC + k];
        out[t] = acc * inv[g] + lin_b[k];
    }
}

extern "C" void kernel_launch(void* const* d_in, const int* in_sizes, int n_in,
                              void* d_out, int out_size, void* d_ws, size_t ws_size,
                              hipStream_t stream)
{
    const float* x      = (const float*)d_in[0];
    const int*   eidx   = (const int*)d_in[1];
    const int*   batch  = (const int*)d_in[2];
    const float* W1     = (const float*)d_in[3];
    const float* att_s1 = (const float*)d_in[4];
    const float* att_d1 = (const float*)d_in[5];
    const float* b1     = (const float*)d_in[6];
    const float* W2     = (const float*)d_in[7];
    const float* att_s2 = (const float*)d_in[8];
    const float* att_d2 = (const float*)d_in[9];
    const float* b2     = (const float*)d_in[10];
    const float* lin_w  = (const float*)d_in[11];
    const float* lin_b  = (const float*)d_in[12];

    const int Nn  = in_sizes[2];         // 50000
    const int E   = in_sizes[1] / 2;     // 800000
    const int H1_ = 4, C1_ = 64, C2_ = 128, G = 32, NC = 5;
    const int D1 = H1_ * C1_;            // 256
    const int ET = E + Nn;
    const int NBUCK = (Nn + 63) >> 6;    // 782 coarse buckets

    const int* srcp = eidx;
    const int* dstp = eidx + E;

    float* ws = (float*)d_ws;
    size_t off = 0;
    auto alloc = [&](size_t n) { float* p = ws + off; off += n; return p; };
    _Float16* o1h = (_Float16*)alloc((size_t)Nn * D1 / 2);    // fp16 layer-1 out
    _Float16* o2h = (_Float16*)alloc((size_t)Nn * C2_ / 2);   // fp16 layer-2 out
    float* aS1  = alloc((size_t)Nn * H1_);
    float* aD1  = alloc((size_t)Nn * H1_);
    float* aS2  = alloc(Nn);              // contiguous with aD2 for single memset
    float* aD2  = alloc(Nn);
    float* sums = alloc((size_t)G * C2_);
    _Float16* BT1 = (_Float16*)alloc(D1 * 128 / 2);           // [256][128] fp16
    _Float16* BT2 = (_Float16*)alloc(C2_ * 256 / 2);          // [128][256] fp16
    unsigned char* hb1 = (unsigned char*)alloc((size_t)Nn * D1 / 4);   // fp8 h1
    unsigned char* hb2 = (unsigned char*)alloc((size_t)Nn * C2_ / 4);  // fp8 h2
    int* iws    = (int*)(ws + off);
    int* counts = iws;                               // Nn
    int* partial= iws + Nn;                          // Nn
    int* rowptr = iws + 2 * Nn;                      // Nn+1
    int* bsum   = iws + 3 * Nn + 1;                  // 256
    int* ccursor= iws + 3 * Nn + 1 + 256;            // NBUCK (<=1024)
    unsigned int* tmp = (unsigned int*)(iws + 3 * Nn + 1 + 256 + 1024);  // ET
    unsigned short* esrc = (unsigned short*)(tmp + ET);                  // ET u16

    const int NB = (Nn + 255) / 256;
    const int GB = (Nn + 63) / 64;
    const int BINB = (ET + 256 * BIN_EPT - 1) / (256 * BIN_EPT);

    // ---------------- CSR build (two-phase, LDS-aggregated) ----------------
    hipMemsetAsync(counts, 0, (size_t)Nn * 4, stream);
    hipMemsetAsync(aS2, 0, (size_t)2 * Nn * 4, stream);   // aS2+aD2 (gemm2 atomics)
    count_k<<<(ET + 255) / 256, 256, 0, stream>>>(dstp, counts, E, Nn);
    scan1_k<<<NB, 256, 0, stream>>>(counts, partial, bsum, Nn);
    scan2_k<<<1, 256, 0, stream>>>(bsum, NB);
    scan3_k<<<(Nn + 256) / 256, 256, 0, stream>>>(partial, bsum, rowptr, ccursor, Nn, ET);
    binpass_k<<<BINB, 256, 0, stream>>>(srcp, dstp, ccursor, tmp, ET, E, NBUCK);
    fine_k<<<NBUCK, 256, 0, stream>>>(rowptr, tmp, esrc, Nn);

    // ---------------- weight transpose+convert (fp16) ----------------
    convW_k<<<256, 256, 0, stream>>>(W1, W2, BT1, BT2);

    // ---------------- layer 1: fp16 GEMM + fp8 out + logits fused ----------------
    gemm_fused<256, 128, 4, false><<<GB, 256, 0, stream>>>(x, BT1, hb1, att_s1, att_d1,
                                                           aS1, aD1, Nn);
    gather1_k<<<(Nn + 3) / 4, 256, 0, stream>>>(rowptr, esrc, hb1, aS1, aD1, b1, o1h, Nn);

    // ---------------- layer 2: fp16 GEMM + fp8 out + logits fused ----------------
    gemm_fused<128, 256, 1, true><<<GB, 256, 0, stream>>>(o1h, BT2, hb2, att_s2, att_d2,
                                                          aS2, aD2, Nn);
    gather2_k<<<(Nn + 3) / 4, 256, 0, stream>>>(rowptr, esrc, hb2, aS2, aD2, o2h, Nn);

    // ---------------- pool + classifier ----------------
    hipMemsetAsync(sums, 0, (size_t)G * C2_ * 4, stream);
    pool_k<<<GB, C2_, 0, stream>>>(o2h, b2, batch, sums, Nn, C2_);
    final_k<<<1, 256, 0, stream>>>(sums, batch, lin_w, lin_b, (float*)d_out, Nn, G, C2_, NC);
}

// Round 5
// 338.172 us; speedup vs baseline: 1.6531x; 1.0286x over previous
//
#include <hip/hip_runtime.h>
#include <math.h>

#define NEG_SLOPE 0.2f

__device__ inline float lrelu(float x) { return x > 0.f ? x : NEG_SLOPE * x; }

typedef __attribute__((ext_vector_type(8))) _Float16 f16x8;
typedef __attribute__((ext_vector_type(4))) float f32x4;
typedef __attribute__((ext_vector_type(2))) float f32x2;
typedef __attribute__((ext_vector_type(4))) _Float16 h16x4;
typedef __attribute__((ext_vector_type(2))) _Float16 h16x2;

// Convert W1[K1,N1], W2[K2,N2] fp32 -> BT [N][K] fp16 (transposed)
__global__ void convW_k(const float* __restrict__ W1, const float* __restrict__ W2,
                        _Float16* __restrict__ BT1, _Float16* __restrict__ BT2)
{
    int i = blockIdx.x * blockDim.x + threadIdx.x;   // 65536 total
    if (i < 32768) {
        int n = i >> 7, k = i & 127;                 // K=128, N=256
        BT1[(size_t)n * 128 + k] = (_Float16)W1[(size_t)k * 256 + n];
    } else {
        int idx = i - 32768;
        int n = idx >> 8, k = idx & 255;             // K=256, N=128
        BT2[(size_t)n * 256 + k] = (_Float16)W2[(size_t)k * 128 + n];
    }
}

// ---- Fused fp16 MFMA GEMM + fp8 out + attention logits -----------------------
// C = A[M,K] @ W[K,N] (fp16 compute, fp32 acc); epilogue writes HB (fp8 e4m3,
// for the edge-gather) and per-row attn logits aS/aD (fp32 from fp32 acc).
// H=4: direct store head=wave; H=1: atomicAdd. AF16: A is already fp16.
template<int N, int K, int H, bool AF16>
__launch_bounds__(256)
__global__ void gemm_fused(const void* __restrict__ A, const _Float16* __restrict__ BT,
                           unsigned char* __restrict__ HB, const float* __restrict__ att_s,
                           const float* __restrict__ att_d, float* __restrict__ aS,
                           float* __restrict__ aD, int M)
{
    constexpr int ITERS = K / 32;
    constexpr int WN = N / 4;
    constexpr int NT = WN / 16;
    constexpr int NCH = (N * 4) / 256;
    __shared__ unsigned short As[64 * 40] __attribute__((aligned(16)));
    __shared__ unsigned short Bs[N * 40] __attribute__((aligned(16)));
    const int t = threadIdx.x;
    const int wave = t >> 6, lane = t & 63;
    const int quad = lane >> 4, l15 = lane & 15;
    const int rowBase = blockIdx.x * 64;

    f32x4 acc[4][NT];
#pragma unroll
    for (int mi = 0; mi < 4; ++mi)
#pragma unroll
        for (int ni = 0; ni < NT; ++ni)
            acc[mi][ni] = (f32x4){0.f, 0.f, 0.f, 0.f};

    const int ar = t >> 2;             // A-stage row 0..63
    const int ak = (t & 3) << 3;       // A-stage k seg 0,8,16,24
    const int bc = (t * NCH) >> 2;     // B-stage column
    const int bks = (t * NCH) & 3;     // B-stage starting chunk

    for (int it = 0; it < ITERS; ++it) {
        // ---- stage A
        {
            int gr = rowBase + ar;
            f16x8 hv;
#pragma unroll
            for (int j = 0; j < 8; ++j) hv[j] = (_Float16)0.f;
            if (gr < M) {
                if constexpr (AF16) {
                    hv = *(const f16x8*)((const _Float16*)A + (size_t)gr * K + it * 32 + ak);
                } else {
                    const float* ap = (const float*)A + (size_t)gr * K + it * 32 + ak;
                    float4 v0 = *(const float4*)ap;
                    float4 v1 = *(const float4*)(ap + 4);
                    hv[0] = (_Float16)v0.x; hv[1] = (_Float16)v0.y;
                    hv[2] = (_Float16)v0.z; hv[3] = (_Float16)v0.w;
                    hv[4] = (_Float16)v1.x; hv[5] = (_Float16)v1.y;
                    hv[6] = (_Float16)v1.z; hv[7] = (_Float16)v1.w;
                }
            }
            *(f16x8*)&As[ar * 40 + ak] = hv;
        }
        // ---- stage B (pre-converted fp16, contiguous copy)
        {
            const _Float16* bp = BT + (size_t)bc * K + it * 32 + bks * 8;
            unsigned short* dp = &Bs[bc * 40 + bks * 8];
#pragma unroll
            for (int j = 0; j < NCH; ++j)
                *(f16x8*)(dp + j * 8) = *(const f16x8*)(bp + j * 8);
        }
        __syncthreads();
        f16x8 af[4], bfr[NT];
#pragma unroll
        for (int mi = 0; mi < 4; ++mi)
            af[mi] = *(const f16x8*)&As[(mi * 16 + l15) * 40 + quad * 8];
#pragma unroll
        for (int ni = 0; ni < NT; ++ni)
            bfr[ni] = *(const f16x8*)&Bs[(wave * WN + ni * 16 + l15) * 40 + quad * 8];
#pragma unroll
        for (int mi = 0; mi < 4; ++mi)
#pragma unroll
            for (int ni = 0; ni < NT; ++ni)
                acc[mi][ni] = __builtin_amdgcn_mfma_f32_16x16x32_f16(
                    af[mi], bfr[ni], acc[mi][ni], 0, 0, 0);
        __syncthreads();
    }
    // ---- epilogue: fp8 store + logits. D layout col=lane&15, row=quad*4+reg
    float asv[NT], adv[NT];
#pragma unroll
    for (int ni = 0; ni < NT; ++ni) {
        int col = wave * WN + ni * 16 + l15;
        asv[ni] = att_s[col];
        adv[ni] = att_d[col];
    }
#pragma unroll
    for (int mi = 0; mi < 4; ++mi) {
#pragma unroll
        for (int r = 0; r < 4; ++r) {
            int row = rowBase + mi * 16 + quad * 4 + r;
            bool ok = row < M;
            float ss = 0.f, sd = 0.f;
#pragma unroll
            for (int ni = 0; ni < NT; ++ni) {
                float v = acc[mi][ni][r];
                ss += v * asv[ni];
                sd += v * adv[ni];
            }
            // fp8 pack: 2 cols per cvt inst (cols are 16 apart -> byte stores)
#pragma unroll
            for (int ni = 0; ni < NT; ni += 2) {
                int pk = __builtin_amdgcn_cvt_pk_fp8_f32(acc[mi][ni][r],
                                                         acc[mi][ni + 1][r], 0, false);
                if (ok) {
                    HB[(size_t)row * N + wave * WN + ni * 16 + l15] =
                        (unsigned char)(pk & 0xff);
                    HB[(size_t)row * N + wave * WN + (ni + 1) * 16 + l15] =
                        (unsigned char)((pk >> 8) & 0xff);
                }
            }
#pragma unroll
            for (int off = 8; off > 0; off >>= 1) {
                ss += __shfl_xor(ss, off);
                sd += __shfl_xor(sd, off);
            }
            if (ok && l15 == 0) {
                if (H == 4) {
                    aS[row * 4 + wave] = ss;
                    aD[row * 4 + wave] = sd;
                } else {
                    atomicAdd(&aS[row], ss);
                    atomicAdd(&aD[row], sd);
                }
            }
        }
    }
}

// =================== CSR build (two-phase sort, LDS-aggregated) =================
// phase 0: LDS-aggregated bucket counting (782 coarse buckets of 64 nodes).
#define BIN_EPT 32
__launch_bounds__(256)
__global__ void bcount_k(const int* __restrict__ dst, int* __restrict__ bcnt,
                         int ET, int E, int NBUCK)
{
    __shared__ int hist[1024];
    for (int i = threadIdx.x; i < NBUCK; i += 256) hist[i] = 0;
    __syncthreads();
    int e0 = blockIdx.x * (256 * BIN_EPT) + threadIdx.x;
#pragma unroll
    for (int j = 0; j < BIN_EPT; ++j) {
        int e = e0 + j * 256;
        if (e < ET) {
            int d = (e < E) ? dst[e] : (e - E);
            atomicAdd(&hist[d >> 6], 1);
        }
    }
    __syncthreads();
    for (int i = threadIdx.x; i < NBUCK; i += 256) {
        int c = hist[i];
        if (c > 0) atomicAdd(&bcnt[i], c);
    }
}

// phase 0b: single-block scan over buckets -> bucket bases + binpass cursors
__global__ void bscan_k(const int* __restrict__ bcnt, int* __restrict__ bbase,
                        int* __restrict__ ccursor, int nb)
{
    __shared__ int sh[1024];
    int t = threadIdx.x;
    int v = (t < nb) ? bcnt[t] : 0;
    sh[t] = v;
    __syncthreads();
#pragma unroll
    for (int o = 1; o < 1024; o <<= 1) {
        int u = (t >= o) ? sh[t - o] : 0;
        __syncthreads();
        sh[t] += u;
        __syncthreads();
    }
    if (t < nb) {
        int excl = sh[t] - v;
        bbase[t] = excl;
        ccursor[t] = excl;
    }
    if (t == nb - 1) bbase[nb] = sh[t];
}

// phase 1: LDS-aggregated coarse scatter. Each block: 8192 edges, LDS histogram,
// ONE global atomicAdd per (block,bucket), then ranked writes.
// Edge packs fully into u32: src | dst<<16 (both < 65536).
__launch_bounds__(256)
__global__ void binpass_k(const int* __restrict__ src, const int* __restrict__ dst,
                          int* __restrict__ ccursor, unsigned int* __restrict__ tmp,
                          int ET, int E, int NBUCK)
{
    __shared__ int hist[1024];
    for (int i = threadIdx.x; i < NBUCK; i += 256) hist[i] = 0;
    __syncthreads();
    int e0 = blockIdx.x * (256 * BIN_EPT) + threadIdx.x;
    unsigned int ev[BIN_EPT];
    int meta[BIN_EPT];
#pragma unroll
    for (int j = 0; j < BIN_EPT; ++j) {
        int e = e0 + j * 256;
        meta[j] = -1;
        if (e < ET) {
            int s, d;
            if (e < E) { s = src[e]; d = dst[e]; } else { s = e - E; d = s; }
            ev[j] = (unsigned int)s | ((unsigned int)d << 16);
            int b = d >> 6;
            int r = atomicAdd(&hist[b], 1);
            meta[j] = (r << 10) | b;          // rank<8192 (13b) | bucket (10b)
        }
    }
    __syncthreads();
    // reserve global ranges: one atomic per touched bucket per block
    for (int i = threadIdx.x; i < NBUCK; i += 256) {
        int c = hist[i];
        hist[i] = (c > 0) ? atomicAdd(&ccursor[i], c) : 0;
    }
    __syncthreads();
#pragma unroll
    for (int j = 0; j < BIN_EPT; ++j) {
        if (meta[j] >= 0) {
            int b = meta[j] & 1023;
            int r = meta[j] >> 10;
            tmp[hist[b] + r] = ev[j];
        }
    }
}

// phase 2: per-bucket fine placement. Derives per-node counts + rowptr from the
// bucket's own edges (64 LDS counters + LDS scan) -- no global count/scan pass.
__global__ void fine_k(const int* __restrict__ bbase, const unsigned int* __restrict__ tmp,
                       int* __restrict__ rowptr, unsigned short* __restrict__ esrc,
                       int Nn, int ET, int NBUCK)
{
    __shared__ int lcnt[64], lpre[64], lcur[64];
    int t = threadIdx.x;
    int b = blockIdx.x;
    int n0 = b << 6;
    int base = bbase[b];
    int end = bbase[b + 1];
    if (t < 64) lcnt[t] = 0;
    __syncthreads();
    for (int i = base + t; i < end; i += 256)
        atomicAdd(&lcnt[(tmp[i] >> 16) & 63], 1);
    __syncthreads();
    if (t < 64) lpre[t] = lcnt[t];
    __syncthreads();
#pragma unroll
    for (int o = 1; o < 64; o <<= 1) {
        int u = (t < 64 && t >= o) ? lpre[t - o] : 0;
        __syncthreads();
        if (t < 64) lpre[t] += u;
        __syncthreads();
    }
    if (t < 64) {
        int n = n0 + t;
        int excl = lpre[t] - lcnt[t];
        if (n < Nn) {
            rowptr[n] = base + excl;
            lcur[t] = base + excl;
        }
    }
    if (b == NBUCK - 1 && t == 0) rowptr[Nn] = ET;
    __syncthreads();
    for (int i = base + t; i < end; i += 256) {
        unsigned int v = tmp[i];
        int pos = atomicAdd(&lcur[(v >> 16) & 63], 1);
        esrc[pos] = (unsigned short)(v & 0xffffu);
    }
}

// ===== gather layer 1, fp8 h, online softmax, masked 8-edge chunks, fp16 out ===
// Edge ids are wave-uniform: readfirstlane pushes gather addressing to SALU/SMEM.
// Tail edges are folded into the 8-wide path via index clamp + logit mask (-1e30
// -> exp()=0 contribution), eliminating the serialized scalar tail.
__global__ void gather1_k(const int* __restrict__ rp, const unsigned short* __restrict__ esrc,
                          const unsigned char* __restrict__ hb, const float* __restrict__ aS,
                          const float* __restrict__ aD, const float* __restrict__ bias,
                          _Float16* __restrict__ out, int Nn)
{
    int d = blockIdx.x * 4 + (threadIdx.x >> 6);
    int lane = threadIdx.x & 63;
    if (d >= Nn) return;
    int c4 = lane << 2;                 // channel base = byte offset (fp8)
    int head = lane >> 4;
    int p0 = __builtin_amdgcn_readfirstlane(rp[d]);
    int p1 = __builtin_amdgcn_readfirstlane(rp[d + 1]);
    float adh = aD[d * 4 + head];
    const float* aSh = aS + head;
    float m = -1e30f, den = 0.f;
    float ax = 0.f, ay = 0.f, az = 0.f, aw = 0.f;
    for (int p = p0; p < p1; p += 8) {
        int nv = p1 - p;                // >=1; chunk has min(nv,8) valid edges
        int s[8];
        float l[8];
#pragma unroll
        for (int j = 0; j < 8; ++j) {
            int e = p + j;
            e = e < p1 ? e : p1 - 1;    // scalar clamp (stays in-bounds)
            s[j] = __builtin_amdgcn_readfirstlane(esrc[e]);
        }
#pragma unroll
        for (int j = 0; j < 8; ++j) {
            float lj = lrelu(aSh[s[j] * 4] + adh);
            l[j] = (j < nv) ? lj : -1e30f;
        }
        float lm = l[0];
#pragma unroll
        for (int j = 1; j < 8; ++j) lm = fmaxf(lm, l[j]);
        if (lm > m) {
            float r = __expf(m - lm);
            ax *= r; ay *= r; az *= r; aw *= r; den *= r;
            m = lm;
        }
        unsigned int v[8];
#pragma unroll
        for (int j = 0; j < 8; ++j)
            v[j] = *(const unsigned int*)&hb[(size_t)s[j] * 256 + c4];
#pragma unroll
        for (int j = 0; j < 8; ++j) {
            float w = __expf(l[j] - m);
            den += w;
            f32x2 lo = __builtin_amdgcn_cvt_pk_f32_fp8((int)v[j], false);
            f32x2 hi = __builtin_amdgcn_cvt_pk_f32_fp8((int)v[j], true);
            ax += lo[0] * w;
            ay += lo[1] * w;
            az += hi[0] * w;
            aw += hi[1] * w;
        }
    }
    float inv = 1.f / (den + 1e-16f);
    float4 b4 = *(const float4*)&bias[c4];
    float rx, ry, rz, rw;
    rx = ax * inv + b4.x; rx = rx > 0.f ? rx : expm1f(rx);
    ry = ay * inv + b4.y; ry = ry > 0.f ? ry : expm1f(ry);
    rz = az * inv + b4.z; rz = rz > 0.f ? rz : expm1f(rz);
    rw = aw * inv + b4.w; rw = rw > 0.f ? rw : expm1f(rw);
    h16x4 r16;
    r16[0] = (_Float16)rx; r16[1] = (_Float16)ry;
    r16[2] = (_Float16)rz; r16[3] = (_Float16)rw;
    *(h16x4*)&out[(size_t)d * 256 + c4] = r16;
}

// ===== gather layer 2: full wave per dst, 2 ch/lane, fp8 h, masked chunks ======
__global__ void gather2_k(const int* __restrict__ rp, const unsigned short* __restrict__ esrc,
                          const unsigned char* __restrict__ hb, const float* __restrict__ aS,
                          const float* __restrict__ aD, _Float16* __restrict__ out, int Nn)
{
    int d = blockIdx.x * 4 + (threadIdx.x >> 6);
    int lane = threadIdx.x & 63;
    if (d >= Nn) return;
    int c2 = lane << 1;                 // channel base = byte offset (fp8)
    int p0 = __builtin_amdgcn_readfirstlane(rp[d]);
    int p1 = __builtin_amdgcn_readfirstlane(rp[d + 1]);
    float adh = aD[d];
    float m = -1e30f, den = 0.f;
    float ax = 0.f, ay = 0.f;
    for (int p = p0; p < p1; p += 8) {
        int nv = p1 - p;
        int s[8];
        float l[8];
#pragma unroll
        for (int j = 0; j < 8; ++j) {
            int e = p + j;
            e = e < p1 ? e : p1 - 1;
            s[j] = __builtin_amdgcn_readfirstlane(esrc[e]);
        }
#pragma unroll
        for (int j = 0; j < 8; ++j) {
            float lj = lrelu(aS[s[j]] + adh);
            l[j] = (j < nv) ? lj : -1e30f;
        }
        float lm = l[0];
#pragma unroll
        for (int j = 1; j < 8; ++j) lm = fmaxf(lm, l[j]);
        if (lm > m) {
            float r = __expf(m - lm);
            ax *= r; ay *= r; den *= r;
            m = lm;
        }
        unsigned short v[8];
#pragma unroll
        for (int j = 0; j < 8; ++j)
            v[j] = *(const unsigned short*)&hb[(size_t)s[j] * 128 + c2];
#pragma unroll
        for (int j = 0; j < 8; ++j) {
            float w = __expf(l[j] - m);
            den += w;
            f32x2 lo = __builtin_amdgcn_cvt_pk_f32_fp8((int)v[j], false);
            ax += lo[0] * w;
            ay += lo[1] * w;
        }
    }
    float inv = 1.f / (den + 1e-16f);
    h16x2 r16;
    r16[0] = (_Float16)(ax * inv);
    r16[1] = (_Float16)(ay * inv);
    *(h16x2*)&out[(size_t)d * 128 + c2] = r16;
}

// batch is sorted; per-block run-length accumulate then atomicAdd per graph run
__global__ void pool_k(const _Float16* __restrict__ o2, const float* __restrict__ b2,
                       const int* __restrict__ batch, float* __restrict__ sums, int Nn, int C)
{
    int c = threadIdx.x;               // C = 128
    int n0 = blockIdx.x * 64;
    int n1 = min(n0 + 64, Nn);
    float local = 0.f;
    int gcur = batch[n0];
    float bc = b2[c];
    for (int n = n0; n < n1; ++n) {
        int g = batch[n];
        if (g != gcur) {
            atomicAdd(&sums[gcur * C + c], local);
            local = 0.f;
            gcur = g;
        }
        float v = (float)o2[(size_t)n * C + c] + bc;
        local += v > 0.f ? v : expm1f(v);
    }
    atomicAdd(&sums[gcur * C + c], local);
}

__global__ void final_k(const float* __restrict__ sums, const int* __restrict__ batch,
                        const float* __restrict__ lin_w, const float* __restrict__ lin_b,
                        float* __restrict__ out, int Nn, int G, int C, int NC)
{
    __shared__ float inv[64];
    int t = threadIdx.x;
    if (t < G) {
        int lo = 0, hi = Nn;
        while (lo < hi) { int mid = (lo + hi) >> 1; if (batch[mid] < t) lo = mid + 1; else hi = mid; }
        int lb = lo;
        lo = 0; hi = Nn;
        while (lo < hi) { int mid = (lo + hi) >> 1; if (batch[mid] < t + 1) lo = mid + 1; else hi = mid; }
        int cnt = lo - lb;
        inv[t] = 1.f / fmaxf((float)cnt, 1.f);
    }
    __syncthreads();
    if (t < G * NC) {
        int g = t / NC, k = t % NC;
        float acc = 0.f;
        for (int c = 0; c < C; ++c) acc += sums[g * C + c] * lin_w[c * NC + k];
        out[t] = acc * inv[g] + lin_b[k];
    }
}

extern "C" void kernel_launch(void* const* d_in, const int* in_sizes, int n_in,
                              void* d_out, int out_size, void* d_ws, size_t ws_size,
                              hipStream_t stream)
{
    const float* x      = (const float*)d_in[0];
    const int*   eidx   = (const int*)d_in[1];
    const int*   batch  = (const int*)d_in[2];
    const float* W1     = (const float*)d_in[3];
    const float* att_s1 = (const float*)d_in[4];
    const float* att_d1 = (const float*)d_in[5];
    const float* b1     = (const float*)d_in[6];
    const float* W2     = (const float*)d_in[7];
    const float* att_s2 = (const float*)d_in[8];
    const float* att_d2 = (const float*)d_in[9];
    const float* b2     = (const float*)d_in[10];
    const float* lin_w  = (const float*)d_in[11];
    const float* lin_b  = (const float*)d_in[12];

    const int Nn  = in_sizes[2];         // 50000
    const int E   = in_sizes[1] / 2;     // 800000
    const int H1_ = 4, C1_ = 64, C2_ = 128, G = 32, NC = 5;
    const int D1 = H1_ * C1_;            // 256
    const int ET = E + Nn;
    const int NBUCK = (Nn + 63) >> 6;    // 782 coarse buckets

    const int* srcp = eidx;
    const int* dstp = eidx + E;

    float* ws = (float*)d_ws;
    size_t off = 0;
    auto alloc = [&](size_t n) { float* p = ws + off; off += n; return p; };
    _Float16* o1h = (_Float16*)alloc((size_t)Nn * D1 / 2);    // fp16 layer-1 out
    _Float16* o2h = (_Float16*)alloc((size_t)Nn * C2_ / 2);   // fp16 layer-2 out
    float* aS1  = alloc((size_t)Nn * H1_);
    float* aD1  = alloc((size_t)Nn * H1_);
    float* aS2  = alloc(Nn);              // contiguous with aD2 for single memset
    float* aD2  = alloc(Nn);
    float* sums = alloc((size_t)G * C2_);
    _Float16* BT1 = (_Float16*)alloc(D1 * 128 / 2);           // [256][128] fp16
    _Float16* BT2 = (_Float16*)alloc(C2_ * 256 / 2);          // [128][256] fp16
    unsigned char* hb1 = (unsigned char*)alloc((size_t)Nn * D1 / 4);   // fp8 h1
    unsigned char* hb2 = (unsigned char*)alloc((size_t)Nn * C2_ / 4);  // fp8 h2
    int* iws    = (int*)(ws + off);
    int* rowptr = iws;                               // Nn+1
    int* bcnt   = iws + Nn + 1;                      // 1024
    int* bbase  = iws + Nn + 1 + 1024;               // 1025
    int* ccursor= iws + Nn + 1 + 2049;               // 1024
    unsigned int* tmp = (unsigned int*)(iws + Nn + 1 + 2049 + 1024);   // ET
    unsigned short* esrc = (unsigned short*)(tmp + ET);                // ET u16

    const int GB = (Nn + 63) / 64;
    const int BINB = (ET + 256 * BIN_EPT - 1) / (256 * BIN_EPT);

    // ---------------- CSR build (two-phase, LDS-aggregated, no global count) ----
    hipMemsetAsync(bcnt, 0, 1024 * 4, stream);
    hipMemsetAsync(aS2, 0, (size_t)2 * Nn * 4, stream);   // aS2+aD2 (gemm2 atomics)
    bcount_k<<<BINB, 256, 0, stream>>>(dstp, bcnt, ET, E, NBUCK);
    bscan_k<<<1, 1024, 0, stream>>>(bcnt, bbase, ccursor, NBUCK);
    binpass_k<<<BINB, 256, 0, stream>>>(srcp, dstp, ccursor, tmp, ET, E, NBUCK);
    fine_k<<<NBUCK, 256, 0, stream>>>(bbase, tmp, rowptr, esrc, Nn, ET, NBUCK);

    // ---------------- weight transpose+convert (fp16) ----------------
    convW_k<<<256, 256, 0, stream>>>(W1, W2, BT1, BT2);

    // ---------------- layer 1: fp16 GEMM + fp8 out + logits fused ----------------
    gemm_fused<256, 128, 4, false><<<GB, 256, 0, stream>>>(x, BT1, hb1, att_s1, att_d1,
                                                           aS1, aD1, Nn);
    gather1_k<<<(Nn + 3) / 4, 256, 0, stream>>>(rowptr, esrc, hb1, aS1, aD1, b1, o1h, Nn);

    // ---------------- layer 2: fp16 GEMM + fp8 out + logits fused ----------------
    gemm_fused<128, 256, 1, true><<<GB, 256, 0, stream>>>(o1h, BT2, hb2, att_s2, att_d2,
                                                          aS2, aD2, Nn);
    gather2_k<<<(Nn + 3) / 4, 256, 0, stream>>>(rowptr, esrc, hb2, aS2, aD2, o2h, Nn);

    // ---------------- pool + classifier ----------------
    hipMemsetAsync(sums, 0, (size_t)G * C2_ * 4, stream);
    pool_k<<<GB, C2_, 0, stream>>>(o2h, b2, batch, sums, Nn, C2_);
    final_k<<<1, 256, 0, stream>>>(sums, batch, lin_w, lin_b, (float*)d_out, Nn, G, C2_, NC);
}

// Round 6
// 319.239 us; speedup vs baseline: 1.7511x; 1.0593x over previous
//
#include <hip/hip_runtime.h>
#include <math.h>

#define NEG_SLOPE 0.2f

__device__ inline float lrelu(float x) { return x > 0.f ? x : NEG_SLOPE * x; }

typedef __attribute__((ext_vector_type(8))) _Float16 f16x8;
typedef __attribute__((ext_vector_type(4))) float f32x4;
typedef __attribute__((ext_vector_type(2))) float f32x2;
typedef __attribute__((ext_vector_type(4))) _Float16 h16x4;
typedef __attribute__((ext_vector_type(2))) _Float16 h16x2;

// Convert W1[K1,N1], W2[K2,N2] fp32 -> BT [N][K] fp16 (transposed)
__global__ void convW_k(const float* __restrict__ W1, const float* __restrict__ W2,
                        _Float16* __restrict__ BT1, _Float16* __restrict__ BT2)
{
    int i = blockIdx.x * blockDim.x + threadIdx.x;   // 65536 total
    if (i < 32768) {
        int n = i >> 7, k = i & 127;                 // K=128, N=256
        BT1[(size_t)n * 128 + k] = (_Float16)W1[(size_t)k * 256 + n];
    } else {
        int idx = i - 32768;
        int n = idx >> 8, k = idx & 255;             // K=256, N=128
        BT2[(size_t)n * 256 + k] = (_Float16)W2[(size_t)k * 128 + n];
    }
}

// ---- Fused fp16 MFMA GEMM + fp8 out + attention logits -----------------------
// C = A[M,K] @ W[K,N] (fp16 compute, fp32 acc); epilogue writes HB (fp8 e4m3,
// for the edge-gather) and per-row attn logits aS/aD (fp32 from fp32 acc).
// H=4: direct store head=wave; H=1: atomicAdd. AF16: A is already fp16.
template<int N, int K, int H, bool AF16>
__launch_bounds__(256)
__global__ void gemm_fused(const void* __restrict__ A, const _Float16* __restrict__ BT,
                           unsigned char* __restrict__ HB, const float* __restrict__ att_s,
                           const float* __restrict__ att_d, float* __restrict__ aS,
                           float* __restrict__ aD, int M)
{
    constexpr int ITERS = K / 32;
    constexpr int WN = N / 4;
    constexpr int NT = WN / 16;
    constexpr int NCH = (N * 4) / 256;
    __shared__ unsigned short As[64 * 40] __attribute__((aligned(16)));
    __shared__ unsigned short Bs[N * 40] __attribute__((aligned(16)));
    const int t = threadIdx.x;
    const int wave = t >> 6, lane = t & 63;
    const int quad = lane >> 4, l15 = lane & 15;
    const int rowBase = blockIdx.x * 64;

    f32x4 acc[4][NT];
#pragma unroll
    for (int mi = 0; mi < 4; ++mi)
#pragma unroll
        for (int ni = 0; ni < NT; ++ni)
            acc[mi][ni] = (f32x4){0.f, 0.f, 0.f, 0.f};

    const int ar = t >> 2;             // A-stage row 0..63
    const int ak = (t & 3) << 3;       // A-stage k seg 0,8,16,24
    const int bc = (t * NCH) >> 2;     // B-stage column
    const int bks = (t * NCH) & 3;     // B-stage starting chunk

    for (int it = 0; it < ITERS; ++it) {
        // ---- stage A
        {
            int gr = rowBase + ar;
            f16x8 hv;
#pragma unroll
            for (int j = 0; j < 8; ++j) hv[j] = (_Float16)0.f;
            if (gr < M) {
                if constexpr (AF16) {
                    hv = *(const f16x8*)((const _Float16*)A + (size_t)gr * K + it * 32 + ak);
                } else {
                    const float* ap = (const float*)A + (size_t)gr * K + it * 32 + ak;
                    float4 v0 = *(const float4*)ap;
                    float4 v1 = *(const float4*)(ap + 4);
                    hv[0] = (_Float16)v0.x; hv[1] = (_Float16)v0.y;
                    hv[2] = (_Float16)v0.z; hv[3] = (_Float16)v0.w;
                    hv[4] = (_Float16)v1.x; hv[5] = (_Float16)v1.y;
                    hv[6] = (_Float16)v1.z; hv[7] = (_Float16)v1.w;
                }
            }
            *(f16x8*)&As[ar * 40 + ak] = hv;
        }
        // ---- stage B (pre-converted fp16, contiguous copy)
        {
            const _Float16* bp = BT + (size_t)bc * K + it * 32 + bks * 8;
            unsigned short* dp = &Bs[bc * 40 + bks * 8];
#pragma unroll
            for (int j = 0; j < NCH; ++j)
                *(f16x8*)(dp + j * 8) = *(const f16x8*)(bp + j * 8);
        }
        __syncthreads();
        f16x8 af[4], bfr[NT];
#pragma unroll
        for (int mi = 0; mi < 4; ++mi)
            af[mi] = *(const f16x8*)&As[(mi * 16 + l15) * 40 + quad * 8];
#pragma unroll
        for (int ni = 0; ni < NT; ++ni)
            bfr[ni] = *(const f16x8*)&Bs[(wave * WN + ni * 16 + l15) * 40 + quad * 8];
#pragma unroll
        for (int mi = 0; mi < 4; ++mi)
#pragma unroll
            for (int ni = 0; ni < NT; ++ni)
                acc[mi][ni] = __builtin_amdgcn_mfma_f32_16x16x32_f16(
                    af[mi], bfr[ni], acc[mi][ni], 0, 0, 0);
        __syncthreads();
    }
    // ---- epilogue: fp8 store + logits. D layout col=lane&15, row=quad*4+reg
    float asv[NT], adv[NT];
#pragma unroll
    for (int ni = 0; ni < NT; ++ni) {
        int col = wave * WN + ni * 16 + l15;
        asv[ni] = att_s[col];
        adv[ni] = att_d[col];
    }
#pragma unroll
    for (int mi = 0; mi < 4; ++mi) {
#pragma unroll
        for (int r = 0; r < 4; ++r) {
            int row = rowBase + mi * 16 + quad * 4 + r;
            bool ok = row < M;
            float ss = 0.f, sd = 0.f;
#pragma unroll
            for (int ni = 0; ni < NT; ++ni) {
                float v = acc[mi][ni][r];
                ss += v * asv[ni];
                sd += v * adv[ni];
            }
            // fp8 pack: 2 cols per cvt inst (cols are 16 apart -> byte stores)
#pragma unroll
            for (int ni = 0; ni < NT; ni += 2) {
                int pk = __builtin_amdgcn_cvt_pk_fp8_f32(acc[mi][ni][r],
                                                         acc[mi][ni + 1][r], 0, false);
                if (ok) {
                    HB[(size_t)row * N + wave * WN + ni * 16 + l15] =
                        (unsigned char)(pk & 0xff);
                    HB[(size_t)row * N + wave * WN + (ni + 1) * 16 + l15] =
                        (unsigned char)((pk >> 8) & 0xff);
                }
            }
#pragma unroll
            for (int off = 8; off > 0; off >>= 1) {
                ss += __shfl_xor(ss, off);
                sd += __shfl_xor(sd, off);
            }
            if (ok && l15 == 0) {
                if (H == 4) {
                    aS[row * 4 + wave] = ss;
                    aD[row * 4 + wave] = sd;
                } else {
                    atomicAdd(&aS[row], ss);
                    atomicAdd(&aD[row], sd);
                }
            }
        }
    }
}

// =================== CSR build (two-phase sort, LDS-aggregated) =================
// phase 0: LDS-aggregated bucket counting (782 coarse buckets of 64 nodes).
#define BIN_EPT 32
__launch_bounds__(256)
__global__ void bcount_k(const int* __restrict__ dst, int* __restrict__ bcnt,
                         int ET, int E, int NBUCK)
{
    __shared__ int hist[1024];
    for (int i = threadIdx.x; i < NBUCK; i += 256) hist[i] = 0;
    __syncthreads();
    int e0 = blockIdx.x * (256 * BIN_EPT) + threadIdx.x;
#pragma unroll
    for (int j = 0; j < BIN_EPT; ++j) {
        int e = e0 + j * 256;
        if (e < ET) {
            int d = (e < E) ? dst[e] : (e - E);
            atomicAdd(&hist[d >> 6], 1);
        }
    }
    __syncthreads();
    for (int i = threadIdx.x; i < NBUCK; i += 256) {
        int c = hist[i];
        if (c > 0) atomicAdd(&bcnt[i], c);
    }
}

// phase 0b: single-block scan over buckets -> bucket bases + binpass cursors
__global__ void bscan_k(const int* __restrict__ bcnt, int* __restrict__ bbase,
                        int* __restrict__ ccursor, int nb)
{
    __shared__ int sh[1024];
    int t = threadIdx.x;
    int v = (t < nb) ? bcnt[t] : 0;
    sh[t] = v;
    __syncthreads();
#pragma unroll
    for (int o = 1; o < 1024; o <<= 1) {
        int u = (t >= o) ? sh[t - o] : 0;
        __syncthreads();
        sh[t] += u;
        __syncthreads();
    }
    if (t < nb) {
        int excl = sh[t] - v;
        bbase[t] = excl;
        ccursor[t] = excl;
    }
    if (t == nb - 1) bbase[nb] = sh[t];
}

// phase 1: LDS-aggregated coarse scatter. Each block: 8192 edges, LDS histogram,
// ONE global atomicAdd per (block,bucket), then ranked writes.
// Edge packs fully into u32: src | dst<<16 (both < 65536).
__launch_bounds__(256)
__global__ void binpass_k(const int* __restrict__ src, const int* __restrict__ dst,
                          int* __restrict__ ccursor, unsigned int* __restrict__ tmp,
                          int ET, int E, int NBUCK)
{
    __shared__ int hist[1024];
    for (int i = threadIdx.x; i < NBUCK; i += 256) hist[i] = 0;
    __syncthreads();
    int e0 = blockIdx.x * (256 * BIN_EPT) + threadIdx.x;
    unsigned int ev[BIN_EPT];
    int meta[BIN_EPT];
#pragma unroll
    for (int j = 0; j < BIN_EPT; ++j) {
        int e = e0 + j * 256;
        meta[j] = -1;
        if (e < ET) {
            int s, d;
            if (e < E) { s = src[e]; d = dst[e]; } else { s = e - E; d = s; }
            ev[j] = (unsigned int)s | ((unsigned int)d << 16);
            int b = d >> 6;
            int r = atomicAdd(&hist[b], 1);
            meta[j] = (r << 10) | b;          // rank<8192 (13b) | bucket (10b)
        }
    }
    __syncthreads();
    // reserve global ranges: one atomic per touched bucket per block
    for (int i = threadIdx.x; i < NBUCK; i += 256) {
        int c = hist[i];
        hist[i] = (c > 0) ? atomicAdd(&ccursor[i], c) : 0;
    }
    __syncthreads();
#pragma unroll
    for (int j = 0; j < BIN_EPT; ++j) {
        if (meta[j] >= 0) {
            int b = meta[j] & 1023;
            int r = meta[j] >> 10;
            tmp[hist[b] + r] = ev[j];
        }
    }
}

// phase 2: per-bucket fine placement. Derives per-node counts + rowptr from the
// bucket's own edges (64 LDS counters + LDS scan) -- no global count/scan pass.
__global__ void fine_k(const int* __restrict__ bbase, const unsigned int* __restrict__ tmp,
                       int* __restrict__ rowptr, unsigned short* __restrict__ esrc,
                       int Nn, int ET, int NBUCK)
{
    __shared__ int lcnt[64], lpre[64], lcur[64];
    int t = threadIdx.x;
    int b = blockIdx.x;
    int n0 = b << 6;
    int base = bbase[b];
    int end = bbase[b + 1];
    if (t < 64) lcnt[t] = 0;
    __syncthreads();
    for (int i = base + t; i < end; i += 256)
        atomicAdd(&lcnt[(tmp[i] >> 16) & 63], 1);
    __syncthreads();
    if (t < 64) lpre[t] = lcnt[t];
    __syncthreads();
#pragma unroll
    for (int o = 1; o < 64; o <<= 1) {
        int u = (t < 64 && t >= o) ? lpre[t - o] : 0;
        __syncthreads();
        if (t < 64) lpre[t] += u;
        __syncthreads();
    }
    if (t < 64) {
        int n = n0 + t;
        int excl = lpre[t] - lcnt[t];
        if (n < Nn) {
            rowptr[n] = base + excl;
            lcur[t] = base + excl;
        }
    }
    if (b == NBUCK - 1 && t == 0) rowptr[Nn] = ET;
    __syncthreads();
    for (int i = base + t; i < end; i += 256) {
        unsigned int v = tmp[i];
        int pos = atomicAdd(&lcur[(v >> 16) & 63], 1);
        esrc[pos] = (unsigned short)(v & 0xffffu);
    }
}

// ===== gather layer 1, fp8 h, online softmax, 8-edge chunks + batched tail =====
// Edge ids are wave-uniform: readfirstlane pushes gather addressing to SALU/SMEM.
// Tail: rem is wave-uniform -> `if (j < rem)` is a scalar branch that SKIPS the
// load (no dup loads), while all valid loads still issue back-to-back (1 latency).
__global__ void gather1_k(const int* __restrict__ rp, const unsigned short* __restrict__ esrc,
                          const unsigned char* __restrict__ hb, const float* __restrict__ aS,
                          const float* __restrict__ aD, const float* __restrict__ bias,
                          _Float16* __restrict__ out, int Nn)
{
    int d = blockIdx.x * 4 + (threadIdx.x >> 6);
    int lane = threadIdx.x & 63;
    if (d >= Nn) return;
    int c4 = lane << 2;                 // channel base = byte offset (fp8)
    int head = lane >> 4;
    int p0 = __builtin_amdgcn_readfirstlane(rp[d]);
    int p1 = __builtin_amdgcn_readfirstlane(rp[d + 1]);
    float adh = aD[d * 4 + head];
    const float* aSh = aS + head;
    float m = -1e30f, den = 0.f;
    float ax = 0.f, ay = 0.f, az = 0.f, aw = 0.f;
    int p = p0;
    for (; p + 8 <= p1; p += 8) {
        int s[8];
#pragma unroll
        for (int j = 0; j < 8; ++j) s[j] = __builtin_amdgcn_readfirstlane(esrc[p + j]);
        unsigned int v[8];                 // issue vector loads early
#pragma unroll
        for (int j = 0; j < 8; ++j)
            v[j] = *(const unsigned int*)&hb[(size_t)s[j] * 256 + c4];
        float l[8];
#pragma unroll
        for (int j = 0; j < 8; ++j) l[j] = lrelu(aSh[s[j] * 4] + adh);
        float lm = l[0];
#pragma unroll
        for (int j = 1; j < 8; ++j) lm = fmaxf(lm, l[j]);
        if (lm > m) {
            float r = __expf(m - lm);
            ax *= r; ay *= r; az *= r; aw *= r; den *= r;
            m = lm;
        }
#pragma unroll
        for (int j = 0; j < 8; ++j) {
            float w = __expf(l[j] - m);
            den += w;
            f32x2 lo = __builtin_amdgcn_cvt_pk_f32_fp8((int)v[j], false);
            f32x2 hi = __builtin_amdgcn_cvt_pk_f32_fp8((int)v[j], true);
            ax += lo[0] * w;
            ay += lo[1] * w;
            az += hi[0] * w;
            aw += hi[1] * w;
        }
    }
    int rem = p1 - p;                      // 0..7, wave-uniform
    if (rem > 0) {
        int s[8];
        unsigned int v[8];
        float l[8];
#pragma unroll
        for (int j = 0; j < 8; ++j)
            if (j < rem) s[j] = __builtin_amdgcn_readfirstlane(esrc[p + j]);
#pragma unroll
        for (int j = 0; j < 8; ++j)
            if (j < rem) v[j] = *(const unsigned int*)&hb[(size_t)s[j] * 256 + c4];
#pragma unroll
        for (int j = 0; j < 8; ++j) l[j] = -1e30f;
#pragma unroll
        for (int j = 0; j < 8; ++j)
            if (j < rem) l[j] = lrelu(aSh[s[j] * 4] + adh);
        float lm = l[0];
#pragma unroll
        for (int j = 1; j < 8; ++j) lm = fmaxf(lm, l[j]);
        if (lm > m) {
            float r = __expf(m - lm);
            ax *= r; ay *= r; az *= r; aw *= r; den *= r;
            m = lm;
        }
#pragma unroll
        for (int j = 0; j < 8; ++j) {
            if (j < rem) {
                float w = __expf(l[j] - m);
                den += w;
                f32x2 lo = __builtin_amdgcn_cvt_pk_f32_fp8((int)v[j], false);
                f32x2 hi = __builtin_amdgcn_cvt_pk_f32_fp8((int)v[j], true);
                ax += lo[0] * w;
                ay += lo[1] * w;
                az += hi[0] * w;
                aw += hi[1] * w;
            }
        }
    }
    float inv = 1.f / (den + 1e-16f);
    float4 b4 = *(const float4*)&bias[c4];
    float rx, ry, rz, rw;
    rx = ax * inv + b4.x; rx = rx > 0.f ? rx : expm1f(rx);
    ry = ay * inv + b4.y; ry = ry > 0.f ? ry : expm1f(ry);
    rz = az * inv + b4.z; rz = rz > 0.f ? rz : expm1f(rz);
    rw = aw * inv + b4.w; rw = rw > 0.f ? rw : expm1f(rw);
    h16x4 r16;
    r16[0] = (_Float16)rx; r16[1] = (_Float16)ry;
    r16[2] = (_Float16)rz; r16[3] = (_Float16)rw;
    *(h16x4*)&out[(size_t)d * 256 + c4] = r16;
}

// ===== gather layer 2: full wave per dst, 2 ch/lane, fp8 h, batched tail =======
__global__ void gather2_k(const int* __restrict__ rp, const unsigned short* __restrict__ esrc,
                          const unsigned char* __restrict__ hb, const float* __restrict__ aS,
                          const float* __restrict__ aD, _Float16* __restrict__ out, int Nn)
{
    int d = blockIdx.x * 4 + (threadIdx.x >> 6);
    int lane = threadIdx.x & 63;
    if (d >= Nn) return;
    int c2 = lane << 1;                 // channel base = byte offset (fp8)
    int p0 = __builtin_amdgcn_readfirstlane(rp[d]);
    int p1 = __builtin_amdgcn_readfirstlane(rp[d + 1]);
    float adh = aD[d];
    float m = -1e30f, den = 0.f;
    float ax = 0.f, ay = 0.f;
    int p = p0;
    for (; p + 8 <= p1; p += 8) {
        int s[8];
#pragma unroll
        for (int j = 0; j < 8; ++j) s[j] = __builtin_amdgcn_readfirstlane(esrc[p + j]);
        unsigned short v[8];               // issue vector loads early
#pragma unroll
        for (int j = 0; j < 8; ++j)
            v[j] = *(const unsigned short*)&hb[(size_t)s[j] * 128 + c2];
        float l[8];
#pragma unroll
        for (int j = 0; j < 8; ++j) l[j] = lrelu(aS[s[j]] + adh);
        float lm = l[0];
#pragma unroll
        for (int j = 1; j < 8; ++j) lm = fmaxf(lm, l[j]);
        if (lm > m) {
            float r = __expf(m - lm);
            ax *= r; ay *= r; den *= r;
            m = lm;
        }
#pragma unroll
        for (int j = 0; j < 8; ++j) {
            float w = __expf(l[j] - m);
            den += w;
            f32x2 lo = __builtin_amdgcn_cvt_pk_f32_fp8((int)v[j], false);
            ax += lo[0] * w;
            ay += lo[1] * w;
        }
    }
    int rem = p1 - p;                      // 0..7, wave-uniform
    if (rem > 0) {
        int s[8];
        unsigned short v[8];
        float l[8];
#pragma unroll
        for (int j = 0; j < 8; ++j)
            if (j < rem) s[j] = __builtin_amdgcn_readfirstlane(esrc[p + j]);
#pragma unroll
        for (int j = 0; j < 8; ++j)
            if (j < rem) v[j] = *(const unsigned short*)&hb[(size_t)s[j] * 128 + c2];
#pragma unroll
        for (int j = 0; j < 8; ++j) l[j] = -1e30f;
#pragma unroll
        for (int j = 0; j < 8; ++j)
            if (j < rem) l[j] = lrelu(aS[s[j]] + adh);
        float lm = l[0];
#pragma unroll
        for (int j = 1; j < 8; ++j) lm = fmaxf(lm, l[j]);
        if (lm > m) {
            float r = __expf(m - lm);
            ax *= r; ay *= r; den *= r;
            m = lm;
        }
#pragma unroll
        for (int j = 0; j < 8; ++j) {
            if (j < rem) {
                float w = __expf(l[j] - m);
                den += w;
                f32x2 lo = __builtin_amdgcn_cvt_pk_f32_fp8((int)v[j], false);
                ax += lo[0] * w;
                ay += lo[1] * w;
            }
        }
    }
    float inv = 1.f / (den + 1e-16f);
    h16x2 r16;
    r16[0] = (_Float16)(ax * inv);
    r16[1] = (_Float16)(ay * inv);
    *(h16x2*)&out[(size_t)d * 128 + c2] = r16;
}

// batch is sorted; per-block run-length accumulate then atomicAdd per graph run
__global__ void pool_k(const _Float16* __restrict__ o2, const float* __restrict__ b2,
                       const int* __restrict__ batch, float* __restrict__ sums, int Nn, int C)
{
    int c = threadIdx.x;               // C = 128
    int n0 = blockIdx.x * 64;
    int n1 = min(n0 + 64, Nn);
    float local = 0.f;
    int gcur = batch[n0];
    float bc = b2[c];
    for (int n = n0; n < n1; ++n) {
        int g = batch[n];
        if (g != gcur) {
            atomicAdd(&sums[gcur * C + c], local);
            local = 0.f;
            gcur = g;
        }
        float v = (float)o2[(size_t)n * C + c] + bc;
        local += v > 0.f ? v : expm1f(v);
    }
    atomicAdd(&sums[gcur * C + c], local);
}

__global__ void final_k(const float* __restrict__ sums, const int* __restrict__ batch,
                        const float* __restrict__ lin_w, const float* __restrict__ lin_b,
                        float* __restrict__ out, int Nn, int G, int C, int NC)
{
    __shared__ float inv[64];
    int t = threadIdx.x;
    if (t < G) {
        int lo = 0, hi = Nn;
        while (lo < hi) { int mid = (lo + hi) >> 1; if (batch[mid] < t) lo = mid + 1; else hi = mid; }
        int lb = lo;
        lo = 0; hi = Nn;
        while (lo < hi) { int mid = (lo + hi) >> 1; if (batch[mid] < t + 1) lo = mid + 1; else hi = mid; }
        int cnt = lo - lb;
        inv[t] = 1.f / fmaxf((float)cnt, 1.f);
    }
    __syncthreads();
    if (t < G * NC) {
        int g = t / NC, k = t % NC;
        float acc = 0.f;
        for (int c = 0; c < C; ++c) acc += sums[g * C + c] * lin_w[c * NC + k];
        out[t] = acc * inv[g] + lin_b[k];
    }
}

extern "C" void kernel_launch(void* const* d_in, const int* in_sizes, int n_in,
                              void* d_out, int out_size, void* d_ws, size_t ws_size,
                              hipStream_t stream)
{
    const float* x      = (const float*)d_in[0];
    const int*   eidx   = (const int*)d_in[1];
    const int*   batch  = (const int*)d_in[2];
    const float* W1     = (const float*)d_in[3];
    const float* att_s1 = (const float*)d_in[4];
    const float* att_d1 = (const float*)d_in[5];
    const float* b1     = (const float*)d_in[6];
    const float* W2     = (const float*)d_in[7];
    const float* att_s2 = (const float*)d_in[8];
    const float* att_d2 = (const float*)d_in[9];
    const float* b2     = (const float*)d_in[10];
    const float* lin_w  = (const float*)d_in[11];
    const float* lin_b  = (const float*)d_in[12];

    const int Nn  = in_sizes[2];         // 50000
    const int E   = in_sizes[1] / 2;     // 800000
    const int H1_ = 4, C1_ = 64, C2_ = 128, G = 32, NC = 5;
    const int D1 = H1_ * C1_;            // 256
    const int ET = E + Nn;
    const int NBUCK = (Nn + 63) >> 6;    // 782 coarse buckets

    const int* srcp = eidx;
    const int* dstp = eidx + E;

    float* ws = (float*)d_ws;
    size_t off = 0;
    auto alloc = [&](size_t n) { float* p = ws + off; off += n; return p; };
    _Float16* o1h = (_Float16*)alloc((size_t)Nn * D1 / 2);    // fp16 layer-1 out
    _Float16* o2h = (_Float16*)alloc((size_t)Nn * C2_ / 2);   // fp16 layer-2 out
    float* aS1  = alloc((size_t)Nn * H1_);
    float* aD1  = alloc((size_t)Nn * H1_);
    float* aS2  = alloc(Nn);              // contiguous with aD2 for single memset
    float* aD2  = alloc(Nn);
    float* sums = alloc((size_t)G * C2_);
    _Float16* BT1 = (_Float16*)alloc(D1 * 128 / 2);           // [256][128] fp16
    _Float16* BT2 = (_Float16*)alloc(C2_ * 256 / 2);          // [128][256] fp16
    unsigned char* hb1 = (unsigned char*)alloc((size_t)Nn * D1 / 4);   // fp8 h1
    unsigned char* hb2 = (unsigned char*)alloc((size_t)Nn * C2_ / 4);  // fp8 h2
    int* iws    = (int*)(ws + off);
    int* rowptr = iws;                               // Nn+1
    int* bcnt   = iws + Nn + 1;                      // 1024
    int* bbase  = iws + Nn + 1 + 1024;               // 1025
    int* ccursor= iws + Nn + 1 + 2049;               // 1024
    unsigned int* tmp = (unsigned int*)(iws + Nn + 1 + 2049 + 1024);   // ET
    unsigned short* esrc = (unsigned short*)(tmp + ET);                // ET u16

    const int GB = (Nn + 63) / 64;
    const int BINB = (ET + 256 * BIN_EPT - 1) / (256 * BIN_EPT);

    // ---------------- CSR build (two-phase, LDS-aggregated, no global count) ----
    hipMemsetAsync(bcnt, 0, 1024 * 4, stream);
    hipMemsetAsync(aS2, 0, (size_t)2 * Nn * 4, stream);   // aS2+aD2 (gemm2 atomics)
    bcount_k<<<BINB, 256, 0, stream>>>(dstp, bcnt, ET, E, NBUCK);
    bscan_k<<<1, 1024, 0, stream>>>(bcnt, bbase, ccursor, NBUCK);
    binpass_k<<<BINB, 256, 0, stream>>>(srcp, dstp, ccursor, tmp, ET, E, NBUCK);
    fine_k<<<NBUCK, 256, 0, stream>>>(bbase, tmp, rowptr, esrc, Nn, ET, NBUCK);

    // ---------------- weight transpose+convert (fp16) ----------------
    convW_k<<<256, 256, 0, stream>>>(W1, W2, BT1, BT2);

    // ---------------- layer 1: fp16 GEMM + fp8 out + logits fused ----------------
    gemm_fused<256, 128, 4, false><<<GB, 256, 0, stream>>>(x, BT1, hb1, att_s1, att_d1,
                                                           aS1, aD1, Nn);
    gather1_k<<<(Nn + 3) / 4, 256, 0, stream>>>(rowptr, esrc, hb1, aS1, aD1, b1, o1h, Nn);

    // ---------------- layer 2: fp16 GEMM + fp8 out + logits fused ----------------
    gemm_fused<128, 256, 1, true><<<GB, 256, 0, stream>>>(o1h, BT2, hb2, att_s2, att_d2,
                                                          aS2, aD2, Nn);
    gather2_k<<<(Nn + 3) / 4, 256, 0, stream>>>(rowptr, esrc, hb2, aS2, aD2, o2h, Nn);

    // ---------------- pool + classifier ----------------
    hipMemsetAsync(sums, 0, (size_t)G * C2_ * 4, stream);
    pool_k<<<GB, C2_, 0, stream>>>(o2h, b2, batch, sums, Nn, C2_);
    final_k<<<1, 256, 0, stream>>>(sums, batch, lin_w, lin_b, (float*)d_out, Nn, G, C2_, NC);
}